// Round 2
// baseline (578.281 us; speedup 1.0000x reference)
//
#include <hip/hip_runtime.h>
#include <hip/hip_bf16.h>

// Problem constants (match reference)
#define NN 100000
#define CC 200
#define EE 400000
#define GG 512
// H=4 heads, D=50

typedef __bf16 bf16x8 __attribute__((ext_vector_type(8)));
typedef float f32x4 __attribute__((ext_vector_type(4)));

__device__ __forceinline__ float bfraw(unsigned int u) { return __uint_as_float(u << 16); }
__device__ __forceinline__ unsigned short f2bfraw(float f) {
  __hip_bfloat16 b = __float2bfloat16(f);
  union { __hip_bfloat16 b; unsigned short u; } cv; cv.b = b; return cv.u;
}

// ---------- runtime dtype detection (inputs may be fp32/int64 instead of bf16/int32) ----------
// flags[0] = 1 if float inputs are fp32 (ln_w is all-ones: word0 0x3F800000 fp32 vs 0x3F803F80 bf16)
// flags[1] = 1 if int inputs are int64 (odd int32 words of edge_index are all hi-words == 0)
__global__ void k_detect(const unsigned int* __restrict__ lnw_raw,
                         const unsigned int* __restrict__ ei_raw, int* __restrict__ flags) {
  if (threadIdx.x == 0 && blockIdx.x == 0) {
    flags[0] = (lnw_raw[0] == 0x3F800000u) ? 1 : 0;
    flags[1] = (ei_raw[1] == 0u && ei_raw[3] == 0u && ei_raw[5] == 0u && ei_raw[7] == 0u) ? 1 : 0;
  }
}

// canonical int32 copies of edge_index / batch
__global__ void k_cvt_idx(const int* __restrict__ raw, const int* __restrict__ flags,
                          int* __restrict__ out, int count) {
  int i = blockIdx.x * 256 + threadIdx.x;
  if (i >= count) return;
  out[i] = flags[1] ? raw[2 * i] : raw[i];
}

// canonical bf16 copies of all small float params, concatenated:
// [0:200) lnw | [200:400) lnb | [400:40400) W | [40400:40600) attS | [40600:40800) attD
// [40800:41000) bias | [41000:41200) wrel | [41200] brel | [41201:41401) wroot
__global__ void k_cvt_params(const void* lnw, const void* lnb, const void* W,
                             const void* attS, const void* attD, const void* bias,
                             const void* wrel, const void* brel, const void* wroot,
                             const int* __restrict__ flags, unsigned short* __restrict__ out) {
  int i = blockIdx.x * 256 + threadIdx.x;
  if (i >= 41401) return;
  const void* p; int off;
  if (i < 200)        { p = lnw;  off = i; }
  else if (i < 400)   { p = lnb;  off = i - 200; }
  else if (i < 40400) { p = W;    off = i - 400; }
  else if (i < 40600) { p = attS; off = i - 40400; }
  else if (i < 40800) { p = attD; off = i - 40600; }
  else if (i < 41000) { p = bias; off = i - 40800; }
  else if (i < 41200) { p = wrel; off = i - 41000; }
  else if (i < 41201) { p = brel; off = i - 41200; }
  else                { p = wroot; off = i - 41201; }
  out[i] = flags[0] ? f2bfraw(((const float*)p)[off]) : ((const unsigned short*)p)[off];
}

// ---------- graph segment starts (batch is sorted) ----------
__global__ void k_starts(const int* __restrict__ batch, int* __restrict__ starts) {
  int i = blockIdx.x * 256 + threadIdx.x;
  if (i >= NN) return;
  int b = batch[i];
  int pb = (i == 0) ? -1 : batch[i - 1];
  for (int g = pb + 1; g <= b; ++g) starts[g] = i;
  if (i == NN - 1) {
    for (int g = b + 1; g <= GG; ++g) starts[g] = NN;
  }
}

// ---------- per-graph LayerNorm stats ----------
__global__ void k_ln_stats(const void* __restrict__ x, const int* __restrict__ starts,
                           const int* __restrict__ flags,
                           float* __restrict__ mean, float* __restrict__ rstd) {
  __shared__ float sh1[4], sh2[4];
  int g = blockIdx.x;
  int r0 = starts[g], r1 = starts[g + 1];
  float s1 = 0.f, s2 = 0.f;
  if (flags[0]) {       // fp32 input
    const float4* xv = (const float4*)x;
    int i0 = r0 * (CC / 4), i1 = r1 * (CC / 4);
    for (int i = i0 + (int)threadIdx.x; i < i1; i += 256) {
      float4 r = xv[i];
      s1 += r.x + r.y + r.z + r.w;
      s2 += r.x * r.x + r.y * r.y + r.z * r.z + r.w * r.w;
    }
  } else {              // bf16 input
    const uint4* xv = (const uint4*)x;
    int i0 = r0 * (CC / 8), i1 = r1 * (CC / 8);
    for (int i = i0 + (int)threadIdx.x; i < i1; i += 256) {
      uint4 r = xv[i];
      unsigned int w[4] = {r.x, r.y, r.z, r.w};
#pragma unroll
      for (int j = 0; j < 4; ++j) {
        float a = bfraw(w[j] & 0xffffu);
        float b = bfraw(w[j] >> 16);
        s1 += a + b; s2 += a * a + b * b;
      }
    }
  }
#pragma unroll
  for (int o = 32; o > 0; o >>= 1) { s1 += __shfl_down(s1, o, 64); s2 += __shfl_down(s2, o, 64); }
  if ((threadIdx.x & 63) == 0) { sh1[threadIdx.x >> 6] = s1; sh2[threadIdx.x >> 6] = s2; }
  __syncthreads();
  if (threadIdx.x == 0) {
    float t1 = sh1[0] + sh1[1] + sh1[2] + sh1[3];
    float t2 = sh2[0] + sh2[1] + sh2[2] + sh2[3];
    int cnt = r1 - r0;
    if (cnt > 0) {
      float denom = (float)cnt * (float)CC;
      float m = t1 / denom;
      float var = t2 / denom - m * m;
      mean[g] = m;
      rstd[g] = rsqrtf(var + 1e-5f);
    } else { mean[g] = 0.f; rstd[g] = 0.f; }
  }
}

// ---------- normalize + affine + ELU -> h (bf16, staged in d_out) ----------
__global__ void k_norm(const void* __restrict__ x, const int* __restrict__ batch,
                       const float* __restrict__ mean, const float* __restrict__ rstd,
                       const unsigned short* __restrict__ lnw, const unsigned short* __restrict__ lnb,
                       const int* __restrict__ flags, unsigned short* __restrict__ h) {
  int gi = blockIdx.x * 256 + threadIdx.x;     // one 8-elem group per thread; 25 groups/row
  if (gi >= NN * 25) return;
  int row = gi / 25, sub = gi - row * 25;
  int b = batch[row];
  float m = mean[b], rs = rstd[b];
  int cbase = sub * 8;
  float v[8];
  if (flags[0]) {
    const float* xf = (const float*)x + row * CC + cbase;
    float4 r0 = *(const float4*)xf, r1 = *(const float4*)(xf + 4);
    v[0]=r0.x; v[1]=r0.y; v[2]=r0.z; v[3]=r0.w; v[4]=r1.x; v[5]=r1.y; v[6]=r1.z; v[7]=r1.w;
  } else {
    uint4 r = *(const uint4*)((const unsigned short*)x + row * CC + cbase);
    unsigned int w[4] = {r.x, r.y, r.z, r.w};
#pragma unroll
    for (int j = 0; j < 4; ++j) { v[2*j] = bfraw(w[j] & 0xffffu); v[2*j+1] = bfraw(w[j] >> 16); }
  }
  unsigned int o[4];
#pragma unroll
  for (int j = 0; j < 4; ++j) {
    int c0 = cbase + 2 * j;
    float ta = (v[2*j]   - m) * rs * bfraw(lnw[c0])     + bfraw(lnb[c0]);
    float tb = (v[2*j+1] - m) * rs * bfraw(lnw[c0 + 1]) + bfraw(lnb[c0 + 1]);
    ta = ta > 0.f ? ta : expm1f(ta);
    tb = tb > 0.f ? tb : expm1f(tb);
    o[j] = (unsigned int)f2bfraw(ta) | ((unsigned int)f2bfraw(tb) << 16);
  }
  *(uint4*)(h + row * CC + cbase) = make_uint4(o[0], o[1], o[2], o[3]);
}

// ---------- pack W into MFMA B-fragment order: [(t*7+s)*64+lane]*8+j, zero-padded ----------
__global__ void k_wpack(const unsigned short* __restrict__ W, unsigned short* __restrict__ wp) {
  int idx = blockIdx.x * 256 + threadIdx.x;
  if (idx >= 13 * 7 * 64 * 8) return;
  int j = idx & 7;
  int rest = idx >> 3;
  int l = rest & 63;
  int ts = rest >> 6;
  int s = ts % 7, t = ts / 7;
  int k = s * 32 + (l >> 4) * 8 + j;
  int n = t * 16 + (l & 15);
  wp[idx] = (k < CC && n < CC) ? W[k * CC + n] : (unsigned short)0;
}

// ---------- xh = h @ W via mfma_f32_16x16x32_bf16; one wave = 16 rows x 208 cols ----------
__global__ void k_gemm(const unsigned short* __restrict__ h, const unsigned short* __restrict__ wp,
                       unsigned short* __restrict__ xh) {
  int gw = (blockIdx.x * 256 + threadIdx.x) >> 6;
  int lane = threadIdx.x & 63;
  int mbase = gw * 16;
  if (mbase >= NN) return;
  int quad = lane >> 4, l15 = lane & 15;
  f32x4 acc[13];
#pragma unroll
  for (int t = 0; t < 13; ++t) { f32x4 z = {0.f, 0.f, 0.f, 0.f}; acc[t] = z; }
  // A-frag: row m = mbase + (lane&15), k = s*32 + quad*8 + j. k>=200 reads spill into the
  // next row / d_out tail (finite values) and multiply against zero B-frags -> no effect.
  const unsigned short* hrow = h + (mbase + l15) * CC + quad * 8;
  const bf16x8* wv = (const bf16x8*)wp;
#pragma unroll
  for (int s = 0; s < 7; ++s) {
    bf16x8 af = *(const bf16x8*)(hrow + s * 32);
#pragma unroll
    for (int t = 0; t < 13; ++t) {
      bf16x8 bf = wv[(t * 7 + s) * 64 + lane];
      acc[t] = __builtin_amdgcn_mfma_f32_16x16x32_bf16(af, bf, acc[t], 0, 0, 0);
    }
  }
  // C/D layout: col = lane&15, row = quad*4 + reg
#pragma unroll
  for (int t = 0; t < 13; ++t) {
    int c = t * 16 + l15;
    if (c < CC) {
#pragma unroll
      for (int r = 0; r < 4; ++r) {
        int mrow = mbase + quad * 4 + r;
        xh[mrow * CC + c] = f2bfraw(acc[t][r]);
      }
    }
  }
}

// ---------- attention dot products a_src/a_dst [N,4] ----------
__global__ void k_attdots(const unsigned short* __restrict__ xh, const unsigned short* __restrict__ attS,
                          const unsigned short* __restrict__ attD,
                          float* __restrict__ asrc, float* __restrict__ adst) {
  int idx = blockIdx.x * 256 + threadIdx.x;
  if (idx >= NN * 4) return;
  int n = idx >> 2, hh = idx & 3;
  const unsigned int* row = (const unsigned int*)(xh + n * CC + hh * 50);
  const unsigned int* ws  = (const unsigned int*)(attS + hh * 50);
  const unsigned int* wd  = (const unsigned int*)(attD + hh * 50);
  float s = 0.f, d = 0.f;
#pragma unroll
  for (int i = 0; i < 25; ++i) {
    unsigned int rv = row[i], sv = ws[i], dv = wd[i];
    float a0 = bfraw(rv & 0xffffu), a1 = bfraw(rv >> 16);
    s += a0 * bfraw(sv & 0xffffu) + a1 * bfraw(sv >> 16);
    d += a0 * bfraw(dv & 0xffffu) + a1 * bfraw(dv >> 16);
  }
  asrc[idx] = s; adst[idx] = d;
}

// ---------- CSR build: histogram, scan, scatter ----------
__global__ void k_hist(const int* __restrict__ ei32, int* __restrict__ deg) {
  int e = blockIdx.x * 256 + threadIdx.x;
  if (e >= EE) return;
  atomicAdd(&deg[ei32[EE + e]], 1);
}

__global__ void k_scan1(const int* __restrict__ deg, int* __restrict__ rowptr, int* __restrict__ sums) {
  __shared__ int sh[256];
  int tid = threadIdx.x;
  int base = blockIdx.x * 1024 + tid * 4;
  int v[4]; int s = 0;
#pragma unroll
  for (int j = 0; j < 4; ++j) { int i = base + j; v[j] = (i < NN) ? deg[i] : 0; s += v[j]; }
  sh[tid] = s;
  __syncthreads();
  for (int o = 1; o < 256; o <<= 1) {
    int t = (tid >= o) ? sh[tid - o] : 0;
    __syncthreads();
    sh[tid] += t;
    __syncthreads();
  }
  int run = sh[tid] - s;   // exclusive prefix for this thread
#pragma unroll
  for (int j = 0; j < 4; ++j) { int i = base + j; if (i < NN) rowptr[i] = run; run += v[j]; }
  if (tid == 255) sums[blockIdx.x] = sh[255];
}

__global__ void k_scan2(int* __restrict__ sums, int nb) {
  if (blockIdx.x == 0 && threadIdx.x == 0) {
    int run = 0;
    for (int i = 0; i < nb; ++i) { int t = sums[i]; sums[i] = run; run += t; }
  }
}

__global__ void k_scan3(int* __restrict__ rowptr, const int* __restrict__ sums) {
  int tid = threadIdx.x;
  int add = sums[blockIdx.x];
  int base = blockIdx.x * 1024 + tid * 4;
#pragma unroll
  for (int j = 0; j < 4; ++j) { int i = base + j; if (i < NN) rowptr[i] += add; }
  if (blockIdx.x == 0 && tid == 0) rowptr[NN] = EE;
}

__global__ void k_scatter(const int* __restrict__ ei32, const int* __restrict__ rowptr,
                          int* __restrict__ fill, int* __restrict__ csrc) {
  int e = blockIdx.x * 256 + threadIdx.x;
  if (e >= EE) return;
  int s = ei32[e], d = ei32[EE + e];
  int pos = rowptr[d] + atomicAdd(&fill[d], 1);
  csrc[pos] = s;
}

// ---------- attention: unnormalized exp weights + z per node (self-loop analytic) ----------
__global__ void k_attn_z(const float* __restrict__ asrc, const float* __restrict__ adst,
                         const int* __restrict__ rowptr, const int* __restrict__ csrc,
                         float* __restrict__ att, float* __restrict__ z, float* __restrict__ eself) {
  int n = blockIdx.x * 256 + threadIdx.x;
  if (n >= NN) return;
  float ad[4], zz[4];
#pragma unroll
  for (int hh = 0; hh < 4; ++hh) ad[hh] = adst[n * 4 + hh];
#pragma unroll
  for (int hh = 0; hh < 4; ++hh) {
    float al = asrc[n * 4 + hh] + ad[hh];
    al = al > 0.f ? al : 0.2f * al;
    float e = expf(al);
    eself[n * 4 + hh] = e; zz[hh] = e;
  }
  int p0 = rowptr[n], p1 = rowptr[n + 1];
  for (int p = p0; p < p1; ++p) {
    int s = csrc[p];
#pragma unroll
    for (int hh = 0; hh < 4; ++hh) {
      float al = asrc[s * 4 + hh] + ad[hh];
      al = al > 0.f ? al : 0.2f * al;
      float e = expf(al);
      att[p * 4 + hh] = e; zz[hh] += e;
    }
  }
#pragma unroll
  for (int hh = 0; hh < 4; ++hh) z[n * 4 + hh] = zz[hh];
}

// ---------- out = attention aggregation + bias; fused score dot products ----------
__global__ void k_out(const unsigned short* __restrict__ xh, const float* __restrict__ att,
                      const float* __restrict__ z, const float* __restrict__ eself,
                      const int* __restrict__ rowptr, const int* __restrict__ csrc,
                      const unsigned short* __restrict__ bias, const unsigned short* __restrict__ wrel,
                      const unsigned short* __restrict__ wroot, const int* __restrict__ flags,
                      unsigned short* out_dd, unsigned short* out_ws,
                      float* __restrict__ srel, float* __restrict__ sroot) {
  __shared__ float shA[4], shB[4];
  unsigned short* out = flags[0] ? out_ws : out_dd;   // bf16-out mode stages in d_out (h is dead)
  int n = blockIdx.x;
  int c = threadIdx.x;
  float outv = 0.f;
  if (c < CC) {
    int hh = c / 50;
    float rz = 1.f / (z[n * 4 + hh] + 1e-16f);
    float acc = eself[n * 4 + hh] * bfraw(xh[n * CC + c]);
    int p0 = rowptr[n], p1 = rowptr[n + 1];
    for (int p = p0; p < p1; ++p) {
      int s = csrc[p];
      acc += att[p * 4 + hh] * bfraw(xh[s * CC + c]);
    }
    outv = acc * rz + bfraw(bias[c]);
    out[n * CC + c] = f2bfraw(outv);
  }
  float pr = (c < CC) ? outv * bfraw(wrel[c])  : 0.f;
  float pq = (c < CC) ? outv * bfraw(wroot[c]) : 0.f;
#pragma unroll
  for (int o = 32; o > 0; o >>= 1) { pr += __shfl_down(pr, o, 64); pq += __shfl_down(pq, o, 64); }
  if ((threadIdx.x & 63) == 0) { shA[threadIdx.x >> 6] = pr; shB[threadIdx.x >> 6] = pq; }
  __syncthreads();
  if (threadIdx.x == 0) {
    srel[n]  = shA[0] + shA[1] + shA[2] + shA[3];
    sroot[n] = shB[0] + shB[1] + shB[2] + shB[3];
  }
}

// ---------- SAGPool score: b_rel + out.w_root + sum_in(srel[src]) ----------
__global__ void k_score(const float* __restrict__ srel, const float* __restrict__ sroot,
                        const unsigned short* __restrict__ brel, const int* __restrict__ rowptr,
                        const int* __restrict__ csrc, float* __restrict__ score) {
  int n = blockIdx.x * 256 + threadIdx.x;
  if (n >= NN) return;
  float sc = bfraw(brel[0]) + sroot[n];
  int p0 = rowptr[n], p1 = rowptr[n + 1];
  for (int p = p0; p < p1; ++p) sc += srel[csrc[p]];
  score[n] = sc;
}

// ---------- per-graph softmax stats over score ----------
__global__ void k_gsoftmax(const float* __restrict__ score, const int* __restrict__ starts,
                           float* __restrict__ smax, float* __restrict__ ssum) {
  __shared__ float sh[4];
  __shared__ float bc;
  int g = blockIdx.x;
  int r0 = starts[g], r1 = starts[g + 1];
  float m = -3.0e38f;
  for (int i = r0 + (int)threadIdx.x; i < r1; i += 256) m = fmaxf(m, score[i]);
#pragma unroll
  for (int o = 32; o > 0; o >>= 1) m = fmaxf(m, __shfl_down(m, o, 64));
  if ((threadIdx.x & 63) == 0) sh[threadIdx.x >> 6] = m;
  __syncthreads();
  if (threadIdx.x == 0) bc = fmaxf(fmaxf(sh[0], sh[1]), fmaxf(sh[2], sh[3]));
  __syncthreads();
  float mm = bc;
  float s = 0.f;
  for (int i = r0 + (int)threadIdx.x; i < r1; i += 256) s += expf(score[i] - mm);
#pragma unroll
  for (int o = 32; o > 0; o >>= 1) s += __shfl_down(s, o, 64);
  if ((threadIdx.x & 63) == 0) sh[threadIdx.x >> 6] = s;
  __syncthreads();
  if (threadIdx.x == 0) { smax[g] = mm; ssum[g] = sh[0] + sh[1] + sh[2] + sh[3]; }
}

__global__ void k_scoref(const float* __restrict__ score, const int* __restrict__ batch,
                         const float* __restrict__ smax, const float* __restrict__ ssum,
                         float* __restrict__ scoref) {
  int n = blockIdx.x * 256 + threadIdx.x;
  if (n >= NN) return;
  int b = batch[n];
  float d = ssum[b];
  scoref[n] = (d > 0.f) ? expf(score[n] - smax[b]) / d : 0.f;
}

// ---------- xp = out*score (to d_out) and g = per-graph sum (to d_out tail) ----------
__global__ void k_final(const unsigned short* out_dd, const unsigned short* out_ws,
                        const float* __restrict__ scoref, const int* __restrict__ starts,
                        const int* __restrict__ flags, void* __restrict__ dout) {
  int f32 = flags[0];
  const unsigned short* out = f32 ? out_ws : out_dd;
  int g = blockIdx.x;
  int r0 = starts[g], r1 = starts[g + 1];
  int c = threadIdx.x;
  float acc = 0.f;
  if (c < CC) {
    for (int r = r0; r < r1; ++r) {
      float v = bfraw(out[r * CC + c]) * scoref[r];
      acc += v;
      if (f32) ((float*)dout)[r * CC + c] = v;
      else     ((unsigned short*)dout)[r * CC + c] = f2bfraw(v);
    }
    if (f32) ((float*)dout)[(size_t)NN * CC + g * CC + c] = acc;
    else     ((unsigned short*)dout)[(size_t)NN * CC + g * CC + c] = f2bfraw(acc);
  }
}

// ---------- workspace layout (bytes; 16B-aligned) ----------
constexpr size_t O_FLAGS  = 0;          // 16
constexpr size_t O_STARTS = 16;         // 513*4 -> 2068, pad
constexpr size_t O_MEAN   = 2080;       // 2048
constexpr size_t O_RSTD   = 4128;       // 2048
constexpr size_t O_SMAX   = 6176;       // 2048
constexpr size_t O_SSUM   = 8224;      // 2048
constexpr size_t O_SUMS   = 10272;      // 512
constexpr size_t O_PAR    = 10784;      // 41401*2 = 82802, pad -> 93600
constexpr size_t O_WPACK  = 93600;      // 93184
constexpr size_t O_BATCH  = 186784;     // 400000
constexpr size_t O_EI32   = 586784;     // 3200000
constexpr size_t O_DEG    = 3786784;    // 400000
constexpr size_t O_FILL   = 4186784;    // 400000 (contiguous w/ DEG for one memset)
constexpr size_t O_ROWPTR = 4586784;    // 400128
constexpr size_t O_CSRC   = 4986912;    // 1600000
constexpr size_t O_ASRC   = 6586912;    // 1600000
constexpr size_t O_ADST   = 8186912;    // 1600000
constexpr size_t O_SREL   = 9786912;    // 400000
constexpr size_t O_SROOT  = 10186912;   // 400000
constexpr size_t O_SCORE  = 10586912;   // 400000
constexpr size_t O_SCOREF = 10986912;   // 400000
constexpr size_t O_Z      = 11386912;   // 1600000
constexpr size_t O_ESELF  = 12986912;   // 1600000
constexpr size_t O_ATT    = 14586912;   // 6400000
constexpr size_t O_XH     = 20986912;   // 40000000
constexpr size_t O_OUTF32 = 60986912;   // 40000000 (used only in fp32-output mode)

extern "C" void kernel_launch(void* const* d_in, const int* in_sizes, int n_in,
                              void* d_out, int out_size, void* d_ws, size_t ws_size,
                              hipStream_t stream) {
  const void* x     = d_in[0];
  const int*  ei    = (const int*)d_in[1];
  const int*  batchr= (const int*)d_in[2];
  const void* lnw_r = d_in[3];
  const void* lnb_r = d_in[4];
  const void* Wg_r  = d_in[5];
  const void* attS_r= d_in[6];
  const void* attD_r= d_in[7];
  const void* bias_r= d_in[8];
  const void* wrel_r= d_in[9];
  const void* brel_r= d_in[10];
  const void* wroot_r=d_in[11];

  char* ws = (char*)d_ws;
  int*   flags  = (int*)(ws + O_FLAGS);
  int*   starts = (int*)(ws + O_STARTS);
  float* mean   = (float*)(ws + O_MEAN);
  float* rstd   = (float*)(ws + O_RSTD);
  float* smax   = (float*)(ws + O_SMAX);
  float* ssum   = (float*)(ws + O_SSUM);
  int*   sums   = (int*)(ws + O_SUMS);
  unsigned short* par = (unsigned short*)(ws + O_PAR);
  unsigned short* wpack = (unsigned short*)(ws + O_WPACK);
  int*   batch  = (int*)(ws + O_BATCH);
  int*   ei32   = (int*)(ws + O_EI32);
  int*   deg    = (int*)(ws + O_DEG);
  int*   fill   = (int*)(ws + O_FILL);
  int*   rowptr = (int*)(ws + O_ROWPTR);
  int*   csrc   = (int*)(ws + O_CSRC);
  float* asrc   = (float*)(ws + O_ASRC);
  float* adst   = (float*)(ws + O_ADST);
  float* srel   = (float*)(ws + O_SREL);
  float* sroot  = (float*)(ws + O_SROOT);
  float* score  = (float*)(ws + O_SCORE);
  float* scoref = (float*)(ws + O_SCOREF);
  float* z      = (float*)(ws + O_Z);
  float* eself  = (float*)(ws + O_ESELF);
  float* att    = (float*)(ws + O_ATT);
  unsigned short* xh    = (unsigned short*)(ws + O_XH);
  unsigned short* outws = (unsigned short*)(ws + O_OUTF32);

  // canonical param views
  unsigned short* lnw  = par;
  unsigned short* lnb  = par + 200;
  unsigned short* Wc   = par + 400;
  unsigned short* attS = par + 40400;
  unsigned short* attD = par + 40600;
  unsigned short* bias = par + 40800;
  unsigned short* wrel = par + 41000;
  unsigned short* brel = par + 41200;
  unsigned short* wroot= par + 41201;

  unsigned short* h      = (unsigned short*)d_out;   // d_out start reused as bf16 scratch for h
  unsigned short* out_dd = (unsigned short*)d_out;   // bf16-out mode: out overwrites h in place

  hipMemsetAsync(deg, 0, 800000, stream);            // deg + fill (contiguous)

  k_detect    <<<1, 64, 0, stream>>>((const unsigned int*)lnw_r, (const unsigned int*)ei, flags);
  k_cvt_params<<<162, 256, 0, stream>>>(lnw_r, lnb_r, Wg_r, attS_r, attD_r, bias_r,
                                        wrel_r, brel_r, wroot_r, flags, par);
  k_cvt_idx   <<<(2 * EE + 255) / 256, 256, 0, stream>>>(ei, flags, ei32, 2 * EE);
  k_cvt_idx   <<<(NN + 255) / 256, 256, 0, stream>>>(batchr, flags, batch, NN);
  k_starts    <<<(NN + 255) / 256, 256, 0, stream>>>(batch, starts);
  k_ln_stats  <<<GG, 256, 0, stream>>>(x, starts, flags, mean, rstd);
  k_norm      <<<(NN * 25 + 255) / 256, 256, 0, stream>>>(x, batch, mean, rstd, lnw, lnb, flags, h);
  k_wpack     <<<(13 * 7 * 64 * 8 + 255) / 256, 256, 0, stream>>>(Wc, wpack);
  k_gemm      <<<1563, 256, 0, stream>>>(h, wpack, xh);
  k_attdots   <<<(NN * 4 + 255) / 256, 256, 0, stream>>>(xh, attS, attD, asrc, adst);
  k_hist      <<<(EE + 255) / 256, 256, 0, stream>>>(ei32, deg);
  k_scan1     <<<98, 256, 0, stream>>>(deg, rowptr, sums);
  k_scan2     <<<1, 64, 0, stream>>>(sums, 98);
  k_scan3     <<<98, 256, 0, stream>>>(rowptr, sums);
  k_scatter   <<<(EE + 255) / 256, 256, 0, stream>>>(ei32, rowptr, fill, csrc);
  k_attn_z    <<<(NN + 255) / 256, 256, 0, stream>>>(asrc, adst, rowptr, csrc, att, z, eself);
  k_out       <<<NN, 256, 0, stream>>>(xh, att, z, eself, rowptr, csrc, bias, wrel, wroot,
                                       flags, out_dd, outws, srel, sroot);
  k_score     <<<(NN + 255) / 256, 256, 0, stream>>>(srel, sroot, brel, rowptr, csrc, score);
  k_gsoftmax  <<<GG, 256, 0, stream>>>(score, starts, smax, ssum);
  k_scoref    <<<(NN + 255) / 256, 256, 0, stream>>>(score, batch, smax, ssum, scoref);
  k_final     <<<GG, 256, 0, stream>>>(out_dd, outws, scoref, starts, flags, d_out);
}

// Round 3
// 415.553 us; speedup vs baseline: 1.3916x; 1.3916x over previous
//
#include <hip/hip_runtime.h>
#include <hip/hip_bf16.h>

// Problem constants (match reference)
#define NN 100000
#define CC 200
#define EE 400000
#define GG 512
// H=4 heads, D=50

typedef __bf16 bf16x8 __attribute__((ext_vector_type(8)));
typedef float f32x4 __attribute__((ext_vector_type(4)));

__device__ __forceinline__ float bfraw(unsigned int u) { return __uint_as_float(u << 16); }
__device__ __forceinline__ unsigned short f2bfraw(float f) {
  __hip_bfloat16 b = __float2bfloat16(f);
  union { __hip_bfloat16 b; unsigned short u; } cv; cv.b = b; return cv.u;
}

// ---------- runtime dtype detection ----------
__global__ void k_detect(const unsigned int* __restrict__ lnw_raw,
                         const unsigned int* __restrict__ ei_raw, int* __restrict__ flags) {
  if (threadIdx.x == 0 && blockIdx.x == 0) {
    flags[0] = (lnw_raw[0] == 0x3F800000u) ? 1 : 0;
    flags[1] = (ei_raw[1] == 0u && ei_raw[3] == 0u && ei_raw[5] == 0u && ei_raw[7] == 0u) ? 1 : 0;
  }
}

__global__ void k_cvt_idx(const int* __restrict__ raw, const int* __restrict__ flags,
                          int* __restrict__ out, int count) {
  int i = blockIdx.x * 256 + threadIdx.x;
  if (i >= count) return;
  out[i] = flags[1] ? raw[2 * i] : raw[i];
}

// canonical bf16 param block:
// [0:200) lnw | [200:400) lnb | [400:40400) W | [40400:40600) attS | [40600:40800) attD
// [40800:41000) bias | [41000:41200) wrel | [41200:41400) wroot | [41400] brel
__global__ void k_cvt_params(const void* lnw, const void* lnb, const void* W,
                             const void* attS, const void* attD, const void* bias,
                             const void* wrel, const void* brel, const void* wroot,
                             const int* __restrict__ flags, unsigned short* __restrict__ out) {
  int i = blockIdx.x * 256 + threadIdx.x;
  if (i > 41400) return;
  const void* p; int off;
  if (i < 200)        { p = lnw;  off = i; }
  else if (i < 400)   { p = lnb;  off = i - 200; }
  else if (i < 40400) { p = W;    off = i - 400; }
  else if (i < 40600) { p = attS; off = i - 40400; }
  else if (i < 40800) { p = attD; off = i - 40600; }
  else if (i < 41000) { p = bias; off = i - 40800; }
  else if (i < 41200) { p = wrel; off = i - 41000; }
  else if (i < 41400) { p = wroot; off = i - 41200; }
  else                { p = brel; off = 0; }
  out[i] = flags[0] ? f2bfraw(((const float*)p)[off]) : ((const unsigned short*)p)[off];
}

// ---------- graph segment starts (batch is sorted) ----------
__global__ void k_starts(const int* __restrict__ batch, int* __restrict__ starts) {
  int i = blockIdx.x * 256 + threadIdx.x;
  if (i >= NN) return;
  int b = batch[i];
  int pb = (i == 0) ? -1 : batch[i - 1];
  for (int g = pb + 1; g <= b; ++g) starts[g] = i;
  if (i == NN - 1) {
    for (int g = b + 1; g <= GG; ++g) starts[g] = NN;
  }
}

// ---------- per-graph LayerNorm stats: 8 chunks/graph, fp32 atomic partials ----------
__global__ void k_ln_stats(const void* __restrict__ x, const int* __restrict__ starts,
                           const int* __restrict__ flags, float* __restrict__ gacc) {
  __shared__ float sh1[4], sh2[4];
  int g = blockIdx.x >> 3, chunk = blockIdx.x & 7;
  int r0 = starts[g], r1 = starts[g + 1], cnt = r1 - r0;
  int ra = r0 + (cnt * chunk) / 8;
  int rb = r0 + (cnt * (chunk + 1)) / 8;
  float s1 = 0.f, s2 = 0.f;
  if (flags[0]) {
    const float4* xv = (const float4*)x;
    for (int i = ra * 50 + (int)threadIdx.x; i < rb * 50; i += 256) {
      float4 r = xv[i];
      s1 += r.x + r.y + r.z + r.w;
      s2 += r.x * r.x + r.y * r.y + r.z * r.z + r.w * r.w;
    }
  } else {
    const uint4* xv = (const uint4*)x;
    for (int i = ra * 25 + (int)threadIdx.x; i < rb * 25; i += 256) {
      uint4 r = xv[i];
      unsigned int w[4] = {r.x, r.y, r.z, r.w};
#pragma unroll
      for (int j = 0; j < 4; ++j) {
        float a = bfraw(w[j] & 0xffffu);
        float b = bfraw(w[j] >> 16);
        s1 += a + b; s2 += a * a + b * b;
      }
    }
  }
#pragma unroll
  for (int o = 32; o > 0; o >>= 1) { s1 += __shfl_down(s1, o, 64); s2 += __shfl_down(s2, o, 64); }
  if ((threadIdx.x & 63) == 0) { sh1[threadIdx.x >> 6] = s1; sh2[threadIdx.x >> 6] = s2; }
  __syncthreads();
  if (threadIdx.x == 0) {
    atomicAdd(&gacc[g * 2],     sh1[0] + sh1[1] + sh1[2] + sh1[3]);
    atomicAdd(&gacc[g * 2 + 1], sh2[0] + sh2[1] + sh2[2] + sh2[3]);
  }
}

__global__ void k_ln_fin(const float* __restrict__ gacc, const int* __restrict__ starts,
                         float* __restrict__ mean, float* __restrict__ rstd) {
  int g = blockIdx.x * 64 + threadIdx.x;
  if (g >= GG) return;
  int cnt = starts[g + 1] - starts[g];
  if (cnt > 0) {
    float denom = (float)cnt * (float)CC;
    float m = gacc[g * 2] / denom;
    float var = gacc[g * 2 + 1] / denom - m * m;
    mean[g] = m;
    rstd[g] = rsqrtf(var + 1e-5f);
  } else { mean[g] = 0.f; rstd[g] = 0.f; }
}

// ---------- normalize + affine + ELU -> h (bf16, staged in d_out) ----------
__global__ void k_norm(const void* __restrict__ x, const int* __restrict__ batch,
                       const float* __restrict__ mean, const float* __restrict__ rstd,
                       const unsigned short* __restrict__ lnw, const unsigned short* __restrict__ lnb,
                       const int* __restrict__ flags, unsigned short* __restrict__ h) {
  int gi = blockIdx.x * 256 + threadIdx.x;
  if (gi >= NN * 25) return;
  int row = gi / 25, sub = gi - row * 25;
  int b = batch[row];
  float m = mean[b], rs = rstd[b];
  int cbase = sub * 8;
  float v[8];
  if (flags[0]) {
    const float* xf = (const float*)x + row * CC + cbase;
    float4 r0 = *(const float4*)xf, r1 = *(const float4*)(xf + 4);
    v[0]=r0.x; v[1]=r0.y; v[2]=r0.z; v[3]=r0.w; v[4]=r1.x; v[5]=r1.y; v[6]=r1.z; v[7]=r1.w;
  } else {
    uint4 r = *(const uint4*)((const unsigned short*)x + row * CC + cbase);
    unsigned int w[4] = {r.x, r.y, r.z, r.w};
#pragma unroll
    for (int j = 0; j < 4; ++j) { v[2*j] = bfraw(w[j] & 0xffffu); v[2*j+1] = bfraw(w[j] >> 16); }
  }
  unsigned int o[4];
#pragma unroll
  for (int j = 0; j < 4; ++j) {
    int c0 = cbase + 2 * j;
    float ta = (v[2*j]   - m) * rs * bfraw(lnw[c0])     + bfraw(lnb[c0]);
    float tb = (v[2*j+1] - m) * rs * bfraw(lnw[c0 + 1]) + bfraw(lnb[c0 + 1]);
    ta = ta > 0.f ? ta : expm1f(ta);
    tb = tb > 0.f ? tb : expm1f(tb);
    o[j] = (unsigned int)f2bfraw(ta) | ((unsigned int)f2bfraw(tb) << 16);
  }
  *(uint4*)(h + row * CC + cbase) = make_uint4(o[0], o[1], o[2], o[3]);
}

// ---------- pack W into MFMA B-fragment order ----------
__global__ void k_wpack(const unsigned short* __restrict__ W, unsigned short* __restrict__ wp) {
  int idx = blockIdx.x * 256 + threadIdx.x;
  if (idx >= 13 * 7 * 64 * 8) return;
  int j = idx & 7;
  int rest = idx >> 3;
  int l = rest & 63;
  int ts = rest >> 6;
  int s = ts % 7, t = ts / 7;
  int k = s * 32 + (l >> 4) * 8 + j;
  int n = t * 16 + (l & 15);
  wp[idx] = (k < CC && n < CC) ? W[k * CC + n] : (unsigned short)0;
}

// ---------- xh = h @ W via mfma_f32_16x16x32_bf16 ----------
__global__ void k_gemm(const unsigned short* __restrict__ h, const unsigned short* __restrict__ wp,
                       unsigned short* __restrict__ xh) {
  int gw = (blockIdx.x * 256 + threadIdx.x) >> 6;
  int lane = threadIdx.x & 63;
  int mbase = gw * 16;
  if (mbase >= NN) return;
  int quad = lane >> 4, l15 = lane & 15;
  f32x4 acc[13];
#pragma unroll
  for (int t = 0; t < 13; ++t) { f32x4 z = {0.f, 0.f, 0.f, 0.f}; acc[t] = z; }
  const unsigned short* hrow = h + (mbase + l15) * CC + quad * 8;
  const bf16x8* wv = (const bf16x8*)wp;
#pragma unroll
  for (int s = 0; s < 7; ++s) {
    bf16x8 af = *(const bf16x8*)(hrow + s * 32);
#pragma unroll
    for (int t = 0; t < 13; ++t) {
      bf16x8 bf = wv[(t * 7 + s) * 64 + lane];
      acc[t] = __builtin_amdgcn_mfma_f32_16x16x32_bf16(af, bf, acc[t], 0, 0, 0);
    }
  }
#pragma unroll
  for (int t = 0; t < 13; ++t) {
    int c = t * 16 + l15;
    if (c < CC) {
#pragma unroll
      for (int r = 0; r < 4; ++r) {
        int mrow = mbase + quad * 4 + r;
        xh[mrow * CC + c] = f2bfraw(acc[t][r]);
      }
    }
  }
}

// ---------- attention dot products a_src/a_dst [N,4] ----------
__global__ void k_attdots(const unsigned short* __restrict__ xh, const unsigned short* __restrict__ attS,
                          const unsigned short* __restrict__ attD,
                          float* __restrict__ asrc, float* __restrict__ adst) {
  int idx = blockIdx.x * 256 + threadIdx.x;
  if (idx >= NN * 4) return;
  int n = idx >> 2, hh = idx & 3;
  const unsigned int* row = (const unsigned int*)(xh + n * CC + hh * 50);
  const unsigned int* ws  = (const unsigned int*)(attS + hh * 50);
  const unsigned int* wd  = (const unsigned int*)(attD + hh * 50);
  float s = 0.f, d = 0.f;
#pragma unroll
  for (int i = 0; i < 25; ++i) {
    unsigned int rv = row[i], sv = ws[i], dv = wd[i];
    float a0 = bfraw(rv & 0xffffu), a1 = bfraw(rv >> 16);
    s += a0 * bfraw(sv & 0xffffu) + a1 * bfraw(sv >> 16);
    d += a0 * bfraw(dv & 0xffffu) + a1 * bfraw(dv >> 16);
  }
  asrc[idx] = s; adst[idx] = d;
}

// ---------- CSR build ----------
__global__ void k_hist(const int* __restrict__ ei32, int* __restrict__ deg) {
  int e = blockIdx.x * 256 + threadIdx.x;
  if (e >= EE) return;
  atomicAdd(&deg[ei32[EE + e]], 1);
}

__global__ void k_scan1(const int* __restrict__ deg, int* __restrict__ rowptr, int* __restrict__ sums) {
  __shared__ int sh[256];
  int tid = threadIdx.x;
  int base = blockIdx.x * 1024 + tid * 4;
  int v[4]; int s = 0;
#pragma unroll
  for (int j = 0; j < 4; ++j) { int i = base + j; v[j] = (i < NN) ? deg[i] : 0; s += v[j]; }
  sh[tid] = s;
  __syncthreads();
  for (int o = 1; o < 256; o <<= 1) {
    int t = (tid >= o) ? sh[tid - o] : 0;
    __syncthreads();
    sh[tid] += t;
    __syncthreads();
  }
  int run = sh[tid] - s;
#pragma unroll
  for (int j = 0; j < 4; ++j) { int i = base + j; if (i < NN) rowptr[i] = run; run += v[j]; }
  if (tid == 255) sums[blockIdx.x] = sh[255];
}

__global__ void k_scan2(int* __restrict__ sums, int nb) {
  if (blockIdx.x == 0 && threadIdx.x == 0) {
    int run = 0;
    for (int i = 0; i < nb; ++i) { int t = sums[i]; sums[i] = run; run += t; }
  }
}

__global__ void k_scan3(int* __restrict__ rowptr, const int* __restrict__ sums) {
  int tid = threadIdx.x;
  int add = sums[blockIdx.x];
  int base = blockIdx.x * 1024 + tid * 4;
#pragma unroll
  for (int j = 0; j < 4; ++j) { int i = base + j; if (i < NN) rowptr[i] += add; }
  if (blockIdx.x == 0 && tid == 0) rowptr[NN] = EE;
}

__global__ void k_scatter(const int* __restrict__ ei32, const int* __restrict__ rowptr,
                          int* __restrict__ fill, int* __restrict__ csrc) {
  int e = blockIdx.x * 256 + threadIdx.x;
  if (e >= EE) return;
  int s = ei32[e], d = ei32[EE + e];
  int pos = rowptr[d] + atomicAdd(&fill[d], 1);
  csrc[pos] = s;
}

// ---------- attention exp weights + z per node ----------
__global__ void k_attn_z(const float* __restrict__ asrc, const float* __restrict__ adst,
                         const int* __restrict__ rowptr, const int* __restrict__ csrc,
                         float* __restrict__ att, float* __restrict__ z, float* __restrict__ eself) {
  int n = blockIdx.x * 256 + threadIdx.x;
  if (n >= NN) return;
  float4 ad4 = *(const float4*)(adst + n * 4);
  float4 as4 = *(const float4*)(asrc + n * 4);
  float ade[4] = {ad4.x, ad4.y, ad4.z, ad4.w};
  float ase[4] = {as4.x, as4.y, as4.z, as4.w};
  float zz[4], es[4];
#pragma unroll
  for (int hh = 0; hh < 4; ++hh) {
    float al = ase[hh] + ade[hh];
    al = al > 0.f ? al : 0.2f * al;
    es[hh] = __expf(al); zz[hh] = es[hh];
  }
  *(float4*)(eself + n * 4) = make_float4(es[0], es[1], es[2], es[3]);
  int p0 = rowptr[n], p1 = rowptr[n + 1];
  for (int p = p0; p < p1; ++p) {
    int s = csrc[p];
    float4 av = *(const float4*)(asrc + s * 4);
    float a4[4] = {av.x, av.y, av.z, av.w}, e4[4];
#pragma unroll
    for (int hh = 0; hh < 4; ++hh) {
      float al = a4[hh] + ade[hh];
      al = al > 0.f ? al : 0.2f * al;
      e4[hh] = __expf(al);
      zz[hh] += e4[hh];
    }
    *(float4*)(att + p * 4) = make_float4(e4[0], e4[1], e4[2], e4[3]);
  }
  *(float4*)(z + n * 4) = make_float4(zz[0], zz[1], zz[2], zz[3]);
}

// ---------- out = attention aggregation + bias; fused score dots ----------
// 25 lanes/node x uint4 (8 ch); 10 nodes per 256-thread block
__global__ void k_out(const unsigned short* __restrict__ xh, const float* __restrict__ att,
                      const float* __restrict__ z, const float* __restrict__ eself,
                      const int* __restrict__ rowptr, const int* __restrict__ csrc,
                      const unsigned short* __restrict__ bias, const unsigned short* __restrict__ wrel,
                      const unsigned short* __restrict__ wroot,
                      unsigned short* __restrict__ out,
                      float* __restrict__ srel, float* __restrict__ sroot) {
  __shared__ float sA[256], sB[256];
  int tid = threadIdx.x;
  int local = tid / 25;
  int sub = tid - local * 25;
  int n = blockIdx.x * 10 + local;
  bool active = (local < 10) && (n < NN);
  float pr = 0.f, pq = 0.f;
  if (active) {
    int c0 = sub * 8;
    int hh0 = c0 / 50;
    int hh1 = hh0 < 3 ? hh0 + 1 : hh0;
    int bnd = (hh0 + 1) * 50;
    bool cr[8];
#pragma unroll
    for (int j = 0; j < 8; ++j) cr[j] = (c0 + j) >= bnd;
    float e_lo = eself[n * 4 + hh0], e_hi = eself[n * 4 + hh1];
    float rz_lo = 1.f / (z[n * 4 + hh0] + 1e-16f);
    float rz_hi = 1.f / (z[n * 4 + hh1] + 1e-16f);
    float acc[8];
    uint4 xv = *(const uint4*)(xh + (size_t)n * CC + c0);
    {
      unsigned int w[4] = {xv.x, xv.y, xv.z, xv.w};
#pragma unroll
      for (int j = 0; j < 4; ++j) {
        float lo = bfraw(w[j] & 0xffffu), hi = bfraw(w[j] >> 16);
        acc[2*j]   = (cr[2*j]   ? e_hi : e_lo) * lo;
        acc[2*j+1] = (cr[2*j+1] ? e_hi : e_lo) * hi;
      }
    }
    int p0 = rowptr[n], p1 = rowptr[n + 1];
    for (int p = p0; p < p1; ++p) {
      int s = csrc[p];
      float a_lo = att[p * 4 + hh0];
      float a_hi = att[p * 4 + hh1];
      uint4 gv = *(const uint4*)(xh + (size_t)s * CC + c0);
      unsigned int gw[4] = {gv.x, gv.y, gv.z, gv.w};
#pragma unroll
      for (int j = 0; j < 4; ++j) {
        float lo = bfraw(gw[j] & 0xffffu), hi = bfraw(gw[j] >> 16);
        acc[2*j]   += (cr[2*j]   ? a_hi : a_lo) * lo;
        acc[2*j+1] += (cr[2*j+1] ? a_hi : a_lo) * hi;
      }
    }
    uint4 bv = *(const uint4*)(bias + c0);
    uint4 rv = *(const uint4*)(wrel + c0);
    uint4 qv = *(const uint4*)(wroot + c0);
    unsigned int bw[4] = {bv.x, bv.y, bv.z, bv.w};
    unsigned int rw[4] = {rv.x, rv.y, rv.z, rv.w};
    unsigned int qw[4] = {qv.x, qv.y, qv.z, qv.w};
    unsigned int ow[4];
#pragma unroll
    for (int j = 0; j < 4; ++j) {
      float v0 = acc[2*j]   * (cr[2*j]   ? rz_hi : rz_lo) + bfraw(bw[j] & 0xffffu);
      float v1 = acc[2*j+1] * (cr[2*j+1] ? rz_hi : rz_lo) + bfraw(bw[j] >> 16);
      ow[j] = (unsigned int)f2bfraw(v0) | ((unsigned int)f2bfraw(v1) << 16);
      pr += v0 * bfraw(rw[j] & 0xffffu) + v1 * bfraw(rw[j] >> 16);
      pq += v0 * bfraw(qw[j] & 0xffffu) + v1 * bfraw(qw[j] >> 16);
    }
    *(uint4*)(out + (size_t)n * CC + c0) = make_uint4(ow[0], ow[1], ow[2], ow[3]);
  }
  sA[tid] = pr; sB[tid] = pq;
  __syncthreads();
  if (active && sub == 0) {
    float a = 0.f, b = 0.f;
#pragma unroll
    for (int k = 0; k < 25; ++k) { a += sA[tid + k]; b += sB[tid + k]; }
    srel[n] = a; sroot[n] = b;
  }
}

// ---------- SAGPool score ----------
__global__ void k_score(const float* __restrict__ srel, const float* __restrict__ sroot,
                        const unsigned short* __restrict__ brel, const int* __restrict__ rowptr,
                        const int* __restrict__ csrc, float* __restrict__ score) {
  int n = blockIdx.x * 256 + threadIdx.x;
  if (n >= NN) return;
  float sc = bfraw(brel[0]) + sroot[n];
  int p0 = rowptr[n], p1 = rowptr[n + 1];
  for (int p = p0; p < p1; ++p) sc += srel[csrc[p]];
  score[n] = sc;
}

// ---------- per-graph softmax stats ----------
__global__ void k_gsoftmax(const float* __restrict__ score, const int* __restrict__ starts,
                           float* __restrict__ smax, float* __restrict__ ssum) {
  __shared__ float sh[4];
  __shared__ float bc;
  int g = blockIdx.x;
  int r0 = starts[g], r1 = starts[g + 1];
  float m = -3.0e38f;
  for (int i = r0 + (int)threadIdx.x; i < r1; i += 256) m = fmaxf(m, score[i]);
#pragma unroll
  for (int o = 32; o > 0; o >>= 1) m = fmaxf(m, __shfl_down(m, o, 64));
  if ((threadIdx.x & 63) == 0) sh[threadIdx.x >> 6] = m;
  __syncthreads();
  if (threadIdx.x == 0) bc = fmaxf(fmaxf(sh[0], sh[1]), fmaxf(sh[2], sh[3]));
  __syncthreads();
  float mm = bc;
  float s = 0.f;
  for (int i = r0 + (int)threadIdx.x; i < r1; i += 256) s += expf(score[i] - mm);
#pragma unroll
  for (int o = 32; o > 0; o >>= 1) s += __shfl_down(s, o, 64);
  if ((threadIdx.x & 63) == 0) sh[threadIdx.x >> 6] = s;
  __syncthreads();
  if (threadIdx.x == 0) { smax[g] = mm; ssum[g] = sh[0] + sh[1] + sh[2] + sh[3]; }
}

__global__ void k_scoref(const float* __restrict__ score, const int* __restrict__ batch,
                         const float* __restrict__ smax, const float* __restrict__ ssum,
                         float* __restrict__ scoref) {
  int n = blockIdx.x * 256 + threadIdx.x;
  if (n >= NN) return;
  int b = batch[n];
  float d = ssum[b];
  scoref[n] = (d > 0.f) ? expf(score[n] - smax[b]) / d : 0.f;
}

// ---------- xp = out*score -> d_out (node-parallel streaming) ----------
__global__ void k_xp(const unsigned short* __restrict__ out, const float* __restrict__ scoref,
                     const int* __restrict__ flags, void* __restrict__ dout) {
  int gi = blockIdx.x * 256 + threadIdx.x;
  if (gi >= NN * 25) return;
  int r = gi / 25, sub = gi - r * 25;
  float sf = scoref[r];
  uint4 xv = *(const uint4*)(out + (size_t)r * CC + sub * 8);
  unsigned int w[4] = {xv.x, xv.y, xv.z, xv.w};
  if (flags[0]) {
    float v[8];
#pragma unroll
    for (int j = 0; j < 4; ++j) { v[2*j] = bfraw(w[j] & 0xffffu) * sf; v[2*j+1] = bfraw(w[j] >> 16) * sf; }
    float* dp = (float*)dout + (size_t)r * CC + sub * 8;
    *(float4*)dp       = make_float4(v[0], v[1], v[2], v[3]);
    *(float4*)(dp + 4) = make_float4(v[4], v[5], v[6], v[7]);
  } else {
    unsigned int o[4];
#pragma unroll
    for (int j = 0; j < 4; ++j) {
      float lo = bfraw(w[j] & 0xffffu) * sf, hi = bfraw(w[j] >> 16) * sf;
      o[j] = (unsigned int)f2bfraw(lo) | ((unsigned int)f2bfraw(hi) << 16);
    }
    *(uint4*)((unsigned short*)dout + (size_t)r * CC + sub * 8) = make_uint4(o[0], o[1], o[2], o[3]);
  }
}

// ---------- g = per-graph sum of out*score -> d_out tail ----------
__global__ void k_gsum(const unsigned short* __restrict__ out, const float* __restrict__ scoref,
                       const int* __restrict__ starts, const int* __restrict__ flags,
                       void* __restrict__ dout) {
  __shared__ float part[10][200];
  int tid = threadIdx.x;
  int rg = tid / 25, sub = tid - rg * 25;
  int g = blockIdx.x;
  int r0 = starts[g], r1 = starts[g + 1];
  if (rg < 10) {
    float acc[8];
#pragma unroll
    for (int j = 0; j < 8; ++j) acc[j] = 0.f;
    for (int r = r0 + rg; r < r1; r += 10) {
      float sf = scoref[r];
      uint4 xv = *(const uint4*)(out + (size_t)r * CC + sub * 8);
      unsigned int w[4] = {xv.x, xv.y, xv.z, xv.w};
#pragma unroll
      for (int j = 0; j < 4; ++j) {
        acc[2*j]   += bfraw(w[j] & 0xffffu) * sf;
        acc[2*j+1] += bfraw(w[j] >> 16) * sf;
      }
    }
#pragma unroll
    for (int j = 0; j < 8; ++j) part[rg][sub * 8 + j] = acc[j];
  }
  __syncthreads();
  if (tid < 200) {
    float s = 0.f;
#pragma unroll
    for (int k = 0; k < 10; ++k) s += part[k][tid];
    size_t o = (size_t)NN * CC + (size_t)g * CC + tid;
    if (flags[0]) ((float*)dout)[o] = s;
    else ((unsigned short*)dout)[o] = f2bfraw(s);
  }
}

// ---------- workspace layout (bytes; 16B-aligned) ----------
constexpr size_t O_FLAGS  = 0;
constexpr size_t O_STARTS = 16;
constexpr size_t O_MEAN   = 2080;
constexpr size_t O_RSTD   = 4128;
constexpr size_t O_SMAX   = 6176;
constexpr size_t O_SSUM   = 8224;
constexpr size_t O_SUMS   = 10272;
constexpr size_t O_PAR    = 10784;      // 41401*2, pad -> 93600
constexpr size_t O_WPACK  = 93600;      // 93184
constexpr size_t O_BATCH  = 186784;     // 400000
constexpr size_t O_EI32   = 586784;     // 3200000
constexpr size_t O_DEG    = 3786784;    // 400000
constexpr size_t O_FILL   = 4186784;    // 400000 (contiguous w/ DEG)
constexpr size_t O_ROWPTR = 4586784;    // 400128
constexpr size_t O_CSRC   = 4986912;    // 1600000
constexpr size_t O_ASRC   = 6586912;    // 1600000
constexpr size_t O_ADST   = 8186912;    // 1600000
constexpr size_t O_SREL   = 9786912;    // 400000
constexpr size_t O_SROOT  = 10186912;   // 400000
constexpr size_t O_SCORE  = 10586912;   // 400000
constexpr size_t O_SCOREF = 10986912;   // 400000
constexpr size_t O_Z      = 11386912;   // 1600000
constexpr size_t O_ESELF  = 12986912;   // 1600000
constexpr size_t O_ATT    = 14586912;   // 6400000 (first 4KB doubles as ln gacc, dead by k_attn_z)
constexpr size_t O_XH     = 20986912;   // 40000000
constexpr size_t O_OUT    = 60986912;   // 40000000

extern "C" void kernel_launch(void* const* d_in, const int* in_sizes, int n_in,
                              void* d_out, int out_size, void* d_ws, size_t ws_size,
                              hipStream_t stream) {
  const void* x     = d_in[0];
  const int*  ei    = (const int*)d_in[1];
  const int*  batchr= (const int*)d_in[2];
  const void* lnw_r = d_in[3];
  const void* lnb_r = d_in[4];
  const void* Wg_r  = d_in[5];
  const void* attS_r= d_in[6];
  const void* attD_r= d_in[7];
  const void* bias_r= d_in[8];
  const void* wrel_r= d_in[9];
  const void* brel_r= d_in[10];
  const void* wroot_r=d_in[11];

  char* ws = (char*)d_ws;
  int*   flags  = (int*)(ws + O_FLAGS);
  int*   starts = (int*)(ws + O_STARTS);
  float* mean   = (float*)(ws + O_MEAN);
  float* rstd   = (float*)(ws + O_RSTD);
  float* smax   = (float*)(ws + O_SMAX);
  float* ssum   = (float*)(ws + O_SSUM);
  int*   sums   = (int*)(ws + O_SUMS);
  unsigned short* par = (unsigned short*)(ws + O_PAR);
  unsigned short* wpack = (unsigned short*)(ws + O_WPACK);
  int*   batch  = (int*)(ws + O_BATCH);
  int*   ei32   = (int*)(ws + O_EI32);
  int*   deg    = (int*)(ws + O_DEG);
  int*   fill   = (int*)(ws + O_FILL);
  int*   rowptr = (int*)(ws + O_ROWPTR);
  int*   csrc   = (int*)(ws + O_CSRC);
  float* asrc   = (float*)(ws + O_ASRC);
  float* adst   = (float*)(ws + O_ADST);
  float* srel   = (float*)(ws + O_SREL);
  float* sroot  = (float*)(ws + O_SROOT);
  float* score  = (float*)(ws + O_SCORE);
  float* scoref = (float*)(ws + O_SCOREF);
  float* z      = (float*)(ws + O_Z);
  float* eself  = (float*)(ws + O_ESELF);
  float* att    = (float*)(ws + O_ATT);
  float* gacc   = (float*)(ws + O_ATT);          // reuse: dead before k_attn_z writes att
  unsigned short* xh    = (unsigned short*)(ws + O_XH);
  unsigned short* outws = (unsigned short*)(ws + O_OUT);

  unsigned short* lnw  = par;
  unsigned short* lnb  = par + 200;
  unsigned short* Wc   = par + 400;
  unsigned short* attS = par + 40400;
  unsigned short* attD = par + 40600;
  unsigned short* bias = par + 40800;
  unsigned short* wrel = par + 41000;
  unsigned short* wroot= par + 41200;
  unsigned short* brel = par + 41400;

  unsigned short* h = (unsigned short*)d_out;    // d_out staged as bf16 scratch for h

  hipMemsetAsync(deg, 0, 800000, stream);        // deg + fill
  hipMemsetAsync(gacc, 0, 4096, stream);         // ln stats accumulators

  k_detect    <<<1, 64, 0, stream>>>((const unsigned int*)lnw_r, (const unsigned int*)ei, flags);
  k_cvt_params<<<162, 256, 0, stream>>>(lnw_r, lnb_r, Wg_r, attS_r, attD_r, bias_r,
                                        wrel_r, brel_r, wroot_r, flags, par);
  k_cvt_idx   <<<(2 * EE + 255) / 256, 256, 0, stream>>>(ei, flags, ei32, 2 * EE);
  k_cvt_idx   <<<(NN + 255) / 256, 256, 0, stream>>>(batchr, flags, batch, NN);
  k_starts    <<<(NN + 255) / 256, 256, 0, stream>>>(batch, starts);
  k_ln_stats  <<<GG * 8, 256, 0, stream>>>(x, starts, flags, gacc);
  k_ln_fin    <<<8, 64, 0, stream>>>(gacc, starts, mean, rstd);
  k_norm      <<<(NN * 25 + 255) / 256, 256, 0, stream>>>(x, batch, mean, rstd, lnw, lnb, flags, h);
  k_wpack     <<<(13 * 7 * 64 * 8 + 255) / 256, 256, 0, stream>>>(Wc, wpack);
  k_gemm      <<<1563, 256, 0, stream>>>(h, wpack, xh);
  k_attdots   <<<(NN * 4 + 255) / 256, 256, 0, stream>>>(xh, attS, attD, asrc, adst);
  k_hist      <<<(EE + 255) / 256, 256, 0, stream>>>(ei32, deg);
  k_scan1     <<<98, 256, 0, stream>>>(deg, rowptr, sums);
  k_scan2     <<<1, 64, 0, stream>>>(sums, 98);
  k_scan3     <<<98, 256, 0, stream>>>(rowptr, sums);
  k_scatter   <<<(EE + 255) / 256, 256, 0, stream>>>(ei32, rowptr, fill, csrc);
  k_attn_z    <<<(NN + 255) / 256, 256, 0, stream>>>(asrc, adst, rowptr, csrc, att, z, eself);
  k_out       <<<10000, 256, 0, stream>>>(xh, att, z, eself, rowptr, csrc, bias, wrel, wroot,
                                          outws, srel, sroot);
  k_score     <<<(NN + 255) / 256, 256, 0, stream>>>(srel, sroot, brel, rowptr, csrc, score);
  k_gsoftmax  <<<GG, 256, 0, stream>>>(score, starts, smax, ssum);
  k_scoref    <<<(NN + 255) / 256, 256, 0, stream>>>(score, batch, smax, ssum, scoref);
  k_xp        <<<(NN * 25 + 255) / 256, 256, 0, stream>>>(outws, scoref, flags, d_out);
  k_gsum      <<<GG, 256, 0, stream>>>(outws, scoref, starts, flags, d_out);
}

// Round 4
// 371.955 us; speedup vs baseline: 1.5547x; 1.1172x over previous
//
#include <hip/hip_runtime.h>
#include <hip/hip_bf16.h>

// Problem constants (match reference)
#define NN 100000
#define CC 200
#define EE 400000
#define GG 512
// H=4 heads, D=50

typedef __bf16 bf16x8 __attribute__((ext_vector_type(8)));
typedef float f32x4 __attribute__((ext_vector_type(4)));

__device__ __forceinline__ float bfraw(unsigned int u) { return __uint_as_float(u << 16); }
__device__ __forceinline__ unsigned short f2bfraw(float f) {
  __hip_bfloat16 b = __float2bfloat16(f);
  union { __hip_bfloat16 b; unsigned short u; } cv; cv.b = b; return cv.u;
}

// ---------- runtime dtype detection ----------
__global__ void k_detect(const unsigned int* __restrict__ lnw_raw,
                         const unsigned int* __restrict__ ei_raw, int* __restrict__ flags) {
  if (threadIdx.x == 0 && blockIdx.x == 0) {
    flags[0] = (lnw_raw[0] == 0x3F800000u) ? 1 : 0;
    flags[1] = (ei_raw[1] == 0u && ei_raw[3] == 0u && ei_raw[5] == 0u && ei_raw[7] == 0u) ? 1 : 0;
  }
}

__global__ void k_cvt_idx(const int* __restrict__ raw, const int* __restrict__ flags,
                          int* __restrict__ out, int count) {
  int i = blockIdx.x * 256 + threadIdx.x;
  if (i >= count) return;
  out[i] = flags[1] ? raw[2 * i] : raw[i];
}

// edges convert + fused degree histogram (dst half)
__global__ void k_cvt_edges(const int* __restrict__ raw, const int* __restrict__ flags,
                            int* __restrict__ out, int* __restrict__ deg) {
  int i = blockIdx.x * 256 + threadIdx.x;
  if (i >= 2 * EE) return;
  int v = flags[1] ? raw[2 * i] : raw[i];
  out[i] = v;
  if (i >= EE) atomicAdd(&deg[v], 1);
}

// canonical bf16 param block:
// [0:200) lnw | [200:400) lnb | [400:40400) W | [40400:40600) attS | [40600:40800) attD
// [40800:41000) bias | [41000:41200) wrel | [41200:41400) wroot | [41400] brel
__global__ void k_cvt_params(const void* lnw, const void* lnb, const void* W,
                             const void* attS, const void* attD, const void* bias,
                             const void* wrel, const void* brel, const void* wroot,
                             const int* __restrict__ flags, unsigned short* __restrict__ out) {
  int i = blockIdx.x * 256 + threadIdx.x;
  if (i > 41400) return;
  const void* p; int off;
  if (i < 200)        { p = lnw;  off = i; }
  else if (i < 400)   { p = lnb;  off = i - 200; }
  else if (i < 40400) { p = W;    off = i - 400; }
  else if (i < 40600) { p = attS; off = i - 40400; }
  else if (i < 40800) { p = attD; off = i - 40600; }
  else if (i < 41000) { p = bias; off = i - 40800; }
  else if (i < 41200) { p = wrel; off = i - 41000; }
  else if (i < 41400) { p = wroot; off = i - 41200; }
  else                { p = brel; off = 0; }
  out[i] = flags[0] ? f2bfraw(((const float*)p)[off]) : ((const unsigned short*)p)[off];
}

// ---------- graph segment starts (batch is sorted) ----------
__global__ void k_starts(const int* __restrict__ batch, int* __restrict__ starts) {
  int i = blockIdx.x * 256 + threadIdx.x;
  if (i >= NN) return;
  int b = batch[i];
  int pb = (i == 0) ? -1 : batch[i - 1];
  for (int g = pb + 1; g <= b; ++g) starts[g] = i;
  if (i == NN - 1) {
    for (int g = b + 1; g <= GG; ++g) starts[g] = NN;
  }
}

// ---------- per-graph LayerNorm stats: 8 chunks/graph, fp32 atomic partials ----------
__global__ void k_ln_stats(const void* __restrict__ x, const int* __restrict__ starts,
                           const int* __restrict__ flags, float* __restrict__ gacc) {
  __shared__ float sh1[4], sh2[4];
  int g = blockIdx.x >> 3, chunk = blockIdx.x & 7;
  int r0 = starts[g], r1 = starts[g + 1], cnt = r1 - r0;
  int ra = r0 + (cnt * chunk) / 8;
  int rb = r0 + (cnt * (chunk + 1)) / 8;
  float s1 = 0.f, s2 = 0.f;
  if (flags[0]) {
    const float4* xv = (const float4*)x;
    for (int i = ra * 50 + (int)threadIdx.x; i < rb * 50; i += 256) {
      float4 r = xv[i];
      s1 += r.x + r.y + r.z + r.w;
      s2 += r.x * r.x + r.y * r.y + r.z * r.z + r.w * r.w;
    }
  } else {
    const uint4* xv = (const uint4*)x;
    for (int i = ra * 25 + (int)threadIdx.x; i < rb * 25; i += 256) {
      uint4 r = xv[i];
      unsigned int w[4] = {r.x, r.y, r.z, r.w};
#pragma unroll
      for (int j = 0; j < 4; ++j) {
        float a = bfraw(w[j] & 0xffffu);
        float b = bfraw(w[j] >> 16);
        s1 += a + b; s2 += a * a + b * b;
      }
    }
  }
#pragma unroll
  for (int o = 32; o > 0; o >>= 1) { s1 += __shfl_down(s1, o, 64); s2 += __shfl_down(s2, o, 64); }
  if ((threadIdx.x & 63) == 0) { sh1[threadIdx.x >> 6] = s1; sh2[threadIdx.x >> 6] = s2; }
  __syncthreads();
  if (threadIdx.x == 0) {
    atomicAdd(&gacc[g * 2],     sh1[0] + sh1[1] + sh1[2] + sh1[3]);
    atomicAdd(&gacc[g * 2 + 1], sh2[0] + sh2[1] + sh2[2] + sh2[3]);
  }
}

__global__ void k_ln_fin(const float* __restrict__ gacc, const int* __restrict__ starts,
                         float* __restrict__ mean, float* __restrict__ rstd) {
  int g = blockIdx.x * 64 + threadIdx.x;
  if (g >= GG) return;
  int cnt = starts[g + 1] - starts[g];
  if (cnt > 0) {
    float denom = (float)cnt * (float)CC;
    float m = gacc[g * 2] / denom;
    float var = gacc[g * 2 + 1] / denom - m * m;
    mean[g] = m;
    rstd[g] = rsqrtf(var + 1e-5f);
  } else { mean[g] = 0.f; rstd[g] = 0.f; }
}

// ---------- pack W into MFMA B-fragment order ----------
__global__ void k_wpack(const unsigned short* __restrict__ W, unsigned short* __restrict__ wp) {
  int idx = blockIdx.x * 256 + threadIdx.x;
  if (idx >= 13 * 7 * 64 * 8) return;
  int j = idx & 7;
  int rest = idx >> 3;
  int l = rest & 63;
  int ts = rest >> 6;
  int s = ts % 7, t = ts / 7;
  int k = s * 32 + (l >> 4) * 8 + j;
  int n = t * 16 + (l & 15);
  wp[idx] = (k < CC && n < CC) ? W[k * CC + n] : (unsigned short)0;
}

// ---------- fused LN-normalize + ELU + GEMM: xh = elu(norm(x)) @ W ----------
// A-frag computed in-register from x; no h staging at all.
__global__ void k_ngemm(const void* __restrict__ x, const int* __restrict__ batch,
                        const float* __restrict__ mean, const float* __restrict__ rstd,
                        const unsigned short* __restrict__ lnw, const unsigned short* __restrict__ lnb,
                        const unsigned short* __restrict__ wp, const int* __restrict__ flags,
                        unsigned short* __restrict__ xh) {
  int gw = (blockIdx.x * 256 + threadIdx.x) >> 6;
  int lane = threadIdx.x & 63;
  int mbase = gw * 16;
  if (mbase >= NN) return;
  int quad = lane >> 4, l15 = lane & 15;
  int row = mbase + l15;
  int b = batch[row];
  float m = mean[b], rs = rstd[b];
  bool f32in = flags[0] != 0;
  f32x4 acc[13];
#pragma unroll
  for (int t = 0; t < 13; ++t) { f32x4 zz = {0.f, 0.f, 0.f, 0.f}; acc[t] = zz; }
  const bf16x8* wv = (const bf16x8*)wp;
#pragma unroll
  for (int s = 0; s < 7; ++s) {
    int kb = s * 32 + quad * 8;
    union { bf16x8 v; unsigned short u[8]; unsigned int w[4]; } af;
    if (kb < CC) {   // only s==6 && quad>=1 exceed; those MFMA against zero B-frags
      float v[8];
      if (f32in) {
        const float* xp = (const float*)x + (size_t)row * CC + kb;
        float4 a = *(const float4*)xp, c = *(const float4*)(xp + 4);
        v[0]=a.x; v[1]=a.y; v[2]=a.z; v[3]=a.w; v[4]=c.x; v[5]=c.y; v[6]=c.z; v[7]=c.w;
      } else {
        uint4 r = *(const uint4*)((const unsigned short*)x + (size_t)row * CC + kb);
        unsigned int w[4] = {r.x, r.y, r.z, r.w};
#pragma unroll
        for (int j = 0; j < 4; ++j) { v[2*j] = bfraw(w[j] & 0xffffu); v[2*j+1] = bfraw(w[j] >> 16); }
      }
      uint4 wv4 = *(const uint4*)(lnw + kb);
      uint4 bv4 = *(const uint4*)(lnb + kb);
      unsigned int ww[4] = {wv4.x, wv4.y, wv4.z, wv4.w};
      unsigned int bb[4] = {bv4.x, bv4.y, bv4.z, bv4.w};
#pragma unroll
      for (int j = 0; j < 4; ++j) {
        float t0 = (v[2*j]   - m) * rs * bfraw(ww[j] & 0xffffu) + bfraw(bb[j] & 0xffffu);
        float t1 = (v[2*j+1] - m) * rs * bfraw(ww[j] >> 16)     + bfraw(bb[j] >> 16);
        t0 = t0 > 0.f ? t0 : __expf(t0) - 1.f;
        t1 = t1 > 0.f ? t1 : __expf(t1) - 1.f;
        af.u[2*j]   = f2bfraw(t0);
        af.u[2*j+1] = f2bfraw(t1);
      }
    } else {
#pragma unroll
      for (int j = 0; j < 4; ++j) af.w[j] = 0u;
    }
#pragma unroll
    for (int t = 0; t < 13; ++t) {
      bf16x8 bf = wv[(t * 7 + s) * 64 + lane];
      acc[t] = __builtin_amdgcn_mfma_f32_16x16x32_bf16(af.v, bf, acc[t], 0, 0, 0);
    }
  }
  // C/D layout: col = lane&15, row = quad*4 + reg
#pragma unroll
  for (int t = 0; t < 13; ++t) {
    int c = t * 16 + l15;
    if (c < CC) {
#pragma unroll
      for (int r = 0; r < 4; ++r) {
        int mrow = mbase + quad * 4 + r;
        xh[(size_t)mrow * CC + c] = f2bfraw(acc[t][r]);
      }
    }
  }
}

// ---------- attention dot products a_src/a_dst [N,4] ----------
__global__ void k_attdots(const unsigned short* __restrict__ xh, const unsigned short* __restrict__ attS,
                          const unsigned short* __restrict__ attD,
                          float* __restrict__ asrc, float* __restrict__ adst) {
  int idx = blockIdx.x * 256 + threadIdx.x;
  if (idx >= NN * 4) return;
  int n = idx >> 2, hh = idx & 3;
  const unsigned int* row = (const unsigned int*)(xh + (size_t)n * CC + hh * 50);
  const unsigned int* ws  = (const unsigned int*)(attS + hh * 50);
  const unsigned int* wd  = (const unsigned int*)(attD + hh * 50);
  float s = 0.f, d = 0.f;
#pragma unroll
  for (int i = 0; i < 25; ++i) {
    unsigned int rv = row[i], sv = ws[i], dv = wd[i];
    float a0 = bfraw(rv & 0xffffu), a1 = bfraw(rv >> 16);
    s += a0 * bfraw(sv & 0xffffu) + a1 * bfraw(sv >> 16);
    d += a0 * bfraw(dv & 0xffffu) + a1 * bfraw(dv >> 16);
  }
  asrc[idx] = s; adst[idx] = d;
}

// ---------- CSR build ----------
__global__ void k_scan1(const int* __restrict__ deg, int* __restrict__ rowptr, int* __restrict__ sums) {
  __shared__ int sh[256];
  int tid = threadIdx.x;
  int base = blockIdx.x * 1024 + tid * 4;
  int v[4]; int s = 0;
#pragma unroll
  for (int j = 0; j < 4; ++j) { int i = base + j; v[j] = (i < NN) ? deg[i] : 0; s += v[j]; }
  sh[tid] = s;
  __syncthreads();
  for (int o = 1; o < 256; o <<= 1) {
    int t = (tid >= o) ? sh[tid - o] : 0;
    __syncthreads();
    sh[tid] += t;
    __syncthreads();
  }
  int run = sh[tid] - s;
#pragma unroll
  for (int j = 0; j < 4; ++j) { int i = base + j; if (i < NN) rowptr[i] = run; run += v[j]; }
  if (tid == 255) sums[blockIdx.x] = sh[255];
}

__global__ void k_scan2(int* __restrict__ sums, int nb) {
  __shared__ int sh[128];
  int tid = threadIdx.x;
  int v = (tid < nb) ? sums[tid] : 0;
  sh[tid] = v;
  __syncthreads();
  for (int o = 1; o < 128; o <<= 1) {
    int t = (tid >= o) ? sh[tid - o] : 0;
    __syncthreads();
    sh[tid] += t;
    __syncthreads();
  }
  if (tid < nb) sums[tid] = sh[tid] - v;   // exclusive
}

__global__ void k_scan3(int* __restrict__ rowptr, const int* __restrict__ sums) {
  int tid = threadIdx.x;
  int add = sums[blockIdx.x];
  int base = blockIdx.x * 1024 + tid * 4;
#pragma unroll
  for (int j = 0; j < 4; ++j) { int i = base + j; if (i < NN) rowptr[i] += add; }
  if (blockIdx.x == 0 && tid == 0) rowptr[NN] = EE;
}

__global__ void k_scatter(const int* __restrict__ ei32, const int* __restrict__ rowptr,
                          int* __restrict__ fill, int* __restrict__ csrc) {
  int e = blockIdx.x * 256 + threadIdx.x;
  if (e >= EE) return;
  int s = ei32[e], d = ei32[EE + e];
  int pos = rowptr[d] + atomicAdd(&fill[d], 1);
  csrc[pos] = s;
}

// ---------- attention exp weights + z per node ----------
__global__ void k_attn_z(const float* __restrict__ asrc, const float* __restrict__ adst,
                         const int* __restrict__ rowptr, const int* __restrict__ csrc,
                         float* __restrict__ att, float* __restrict__ z, float* __restrict__ eself) {
  int n = blockIdx.x * 256 + threadIdx.x;
  if (n >= NN) return;
  float4 ad4 = *(const float4*)(adst + (size_t)n * 4);
  float4 as4 = *(const float4*)(asrc + (size_t)n * 4);
  float ade[4] = {ad4.x, ad4.y, ad4.z, ad4.w};
  float ase[4] = {as4.x, as4.y, as4.z, as4.w};
  float zz[4], es[4];
#pragma unroll
  for (int hh = 0; hh < 4; ++hh) {
    float al = ase[hh] + ade[hh];
    al = al > 0.f ? al : 0.2f * al;
    es[hh] = __expf(al); zz[hh] = es[hh];
  }
  *(float4*)(eself + (size_t)n * 4) = make_float4(es[0], es[1], es[2], es[3]);
  int p0 = rowptr[n], p1 = rowptr[n + 1];
  for (int p = p0; p < p1; ++p) {
    int s = csrc[p];
    float4 av = *(const float4*)(asrc + (size_t)s * 4);
    float a4[4] = {av.x, av.y, av.z, av.w}, e4[4];
#pragma unroll
    for (int hh = 0; hh < 4; ++hh) {
      float al = a4[hh] + ade[hh];
      al = al > 0.f ? al : 0.2f * al;
      e4[hh] = __expf(al);
      zz[hh] += e4[hh];
    }
    *(float4*)(att + (size_t)p * 4) = make_float4(e4[0], e4[1], e4[2], e4[3]);
  }
  *(float4*)(z + (size_t)n * 4) = make_float4(zz[0], zz[1], zz[2], zz[3]);
}

// ---------- out = attention aggregation + bias; fused score dots ----------
// 25 lanes/node x uint4 (8 ch); 10 nodes per 256-thread block; edge loop unrolled x2
__global__ void k_out(const unsigned short* __restrict__ xh, const float* __restrict__ att,
                      const float* __restrict__ z, const float* __restrict__ eself,
                      const int* __restrict__ rowptr, const int* __restrict__ csrc,
                      const unsigned short* __restrict__ bias, const unsigned short* __restrict__ wrel,
                      const unsigned short* __restrict__ wroot,
                      unsigned short* __restrict__ out,
                      float* __restrict__ srel, float* __restrict__ sroot) {
  __shared__ float sA[256], sB[256];
  int tid = threadIdx.x;
  int local = tid / 25;
  int sub = tid - local * 25;
  int n = blockIdx.x * 10 + local;
  bool active = (local < 10) && (n < NN);
  float pr = 0.f, pq = 0.f;
  if (active) {
    int c0 = sub * 8;
    int hh0 = c0 / 50;
    int hh1 = hh0 < 3 ? hh0 + 1 : hh0;
    int bnd = (hh0 + 1) * 50;
    bool cr[8];
#pragma unroll
    for (int j = 0; j < 8; ++j) cr[j] = (c0 + j) >= bnd;
    float e_lo = eself[n * 4 + hh0], e_hi = eself[n * 4 + hh1];
    float rz_lo = 1.f / (z[n * 4 + hh0] + 1e-16f);
    float rz_hi = 1.f / (z[n * 4 + hh1] + 1e-16f);
    float acc[8];
    {
      uint4 xv = *(const uint4*)(xh + (size_t)n * CC + c0);
      unsigned int w[4] = {xv.x, xv.y, xv.z, xv.w};
#pragma unroll
      for (int j = 0; j < 4; ++j) {
        float lo = bfraw(w[j] & 0xffffu), hi = bfraw(w[j] >> 16);
        acc[2*j]   = (cr[2*j]   ? e_hi : e_lo) * lo;
        acc[2*j+1] = (cr[2*j+1] ? e_hi : e_lo) * hi;
      }
    }
    int p0 = rowptr[n], p1 = rowptr[n + 1];
    int p = p0;
    for (; p + 2 <= p1; p += 2) {
      int s0 = csrc[p], s1 = csrc[p + 1];
      uint4 g0 = *(const uint4*)(xh + (size_t)s0 * CC + c0);
      uint4 g1 = *(const uint4*)(xh + (size_t)s1 * CC + c0);
      float4 av0 = *(const float4*)(att + (size_t)p * 4);
      float4 av1 = *(const float4*)(att + (size_t)(p + 1) * 4);
      float a0lo = hh0 == 0 ? av0.x : hh0 == 1 ? av0.y : hh0 == 2 ? av0.z : av0.w;
      float a0hi = hh1 == 1 ? av0.y : hh1 == 2 ? av0.z : av0.w;
      float a1lo = hh0 == 0 ? av1.x : hh0 == 1 ? av1.y : hh0 == 2 ? av1.z : av1.w;
      float a1hi = hh1 == 1 ? av1.y : hh1 == 2 ? av1.z : av1.w;
      unsigned int w0[4] = {g0.x, g0.y, g0.z, g0.w};
      unsigned int w1[4] = {g1.x, g1.y, g1.z, g1.w};
#pragma unroll
      for (int j = 0; j < 4; ++j) {
        acc[2*j]   += (cr[2*j]   ? a0hi : a0lo) * bfraw(w0[j] & 0xffffu);
        acc[2*j+1] += (cr[2*j+1] ? a0hi : a0lo) * bfraw(w0[j] >> 16);
      }
#pragma unroll
      for (int j = 0; j < 4; ++j) {
        acc[2*j]   += (cr[2*j]   ? a1hi : a1lo) * bfraw(w1[j] & 0xffffu);
        acc[2*j+1] += (cr[2*j+1] ? a1hi : a1lo) * bfraw(w1[j] >> 16);
      }
    }
    if (p < p1) {
      int s0 = csrc[p];
      uint4 g0 = *(const uint4*)(xh + (size_t)s0 * CC + c0);
      float4 av0 = *(const float4*)(att + (size_t)p * 4);
      float a0lo = hh0 == 0 ? av0.x : hh0 == 1 ? av0.y : hh0 == 2 ? av0.z : av0.w;
      float a0hi = hh1 == 1 ? av0.y : hh1 == 2 ? av0.z : av0.w;
      unsigned int w0[4] = {g0.x, g0.y, g0.z, g0.w};
#pragma unroll
      for (int j = 0; j < 4; ++j) {
        acc[2*j]   += (cr[2*j]   ? a0hi : a0lo) * bfraw(w0[j] & 0xffffu);
        acc[2*j+1] += (cr[2*j+1] ? a0hi : a0lo) * bfraw(w0[j] >> 16);
      }
    }
    uint4 bv = *(const uint4*)(bias + c0);
    uint4 rv = *(const uint4*)(wrel + c0);
    uint4 qv = *(const uint4*)(wroot + c0);
    unsigned int bw[4] = {bv.x, bv.y, bv.z, bv.w};
    unsigned int rw[4] = {rv.x, rv.y, rv.z, rv.w};
    unsigned int qw[4] = {qv.x, qv.y, qv.z, qv.w};
    unsigned int ow[4];
#pragma unroll
    for (int j = 0; j < 4; ++j) {
      float v0 = acc[2*j]   * (cr[2*j]   ? rz_hi : rz_lo) + bfraw(bw[j] & 0xffffu);
      float v1 = acc[2*j+1] * (cr[2*j+1] ? rz_hi : rz_lo) + bfraw(bw[j] >> 16);
      ow[j] = (unsigned int)f2bfraw(v0) | ((unsigned int)f2bfraw(v1) << 16);
      pr += v0 * bfraw(rw[j] & 0xffffu) + v1 * bfraw(rw[j] >> 16);
      pq += v0 * bfraw(qw[j] & 0xffffu) + v1 * bfraw(qw[j] >> 16);
    }
    *(uint4*)(out + (size_t)n * CC + c0) = make_uint4(ow[0], ow[1], ow[2], ow[3]);
  }
  sA[tid] = pr; sB[tid] = pq;
  __syncthreads();
  if (active && sub == 0) {
    float a = 0.f, b = 0.f;
#pragma unroll
    for (int k = 0; k < 25; ++k) { a += sA[tid + k]; b += sB[tid + k]; }
    srel[n] = a; sroot[n] = b;
  }
}

// ---------- SAGPool score (gather unrolled x2) ----------
__global__ void k_score(const float* __restrict__ srel, const float* __restrict__ sroot,
                        const unsigned short* __restrict__ brel, const int* __restrict__ rowptr,
                        const int* __restrict__ csrc, float* __restrict__ score) {
  int n = blockIdx.x * 256 + threadIdx.x;
  if (n >= NN) return;
  float sc = bfraw(brel[0]) + sroot[n];
  int p0 = rowptr[n], p1 = rowptr[n + 1];
  int p = p0;
  float s0 = 0.f, s1 = 0.f;
  for (; p + 2 <= p1; p += 2) { s0 += srel[csrc[p]]; s1 += srel[csrc[p + 1]]; }
  if (p < p1) s0 += srel[csrc[p]];
  score[n] = sc + s0 + s1;
}

// ---------- per-graph softmax stats ----------
__global__ void k_gsoftmax(const float* __restrict__ score, const int* __restrict__ starts,
                           float* __restrict__ smax, float* __restrict__ ssum) {
  __shared__ float sh[4];
  __shared__ float bc;
  int g = blockIdx.x;
  int r0 = starts[g], r1 = starts[g + 1];
  float m = -3.0e38f;
  for (int i = r0 + (int)threadIdx.x; i < r1; i += 256) m = fmaxf(m, score[i]);
#pragma unroll
  for (int o = 32; o > 0; o >>= 1) m = fmaxf(m, __shfl_down(m, o, 64));
  if ((threadIdx.x & 63) == 0) sh[threadIdx.x >> 6] = m;
  __syncthreads();
  if (threadIdx.x == 0) bc = fmaxf(fmaxf(sh[0], sh[1]), fmaxf(sh[2], sh[3]));
  __syncthreads();
  float mm = bc;
  float s = 0.f;
  for (int i = r0 + (int)threadIdx.x; i < r1; i += 256) s += expf(score[i] - mm);
#pragma unroll
  for (int o = 32; o > 0; o >>= 1) s += __shfl_down(s, o, 64);
  if ((threadIdx.x & 63) == 0) sh[threadIdx.x >> 6] = s;
  __syncthreads();
  if (threadIdx.x == 0) { smax[g] = mm; ssum[g] = sh[0] + sh[1] + sh[2] + sh[3]; }
}

__global__ void k_scoref(const float* __restrict__ score, const int* __restrict__ batch,
                         const float* __restrict__ smax, const float* __restrict__ ssum,
                         float* __restrict__ scoref) {
  int n = blockIdx.x * 256 + threadIdx.x;
  if (n >= NN) return;
  int b = batch[n];
  float d = ssum[b];
  scoref[n] = (d > 0.f) ? expf(score[n] - smax[b]) / d : 0.f;
}

// ---------- xp = out*score -> d_out, + per-graph fp32 partial sums (chunked) ----------
__global__ void k_xpg(const unsigned short* __restrict__ out, const float* __restrict__ scoref,
                      const int* __restrict__ starts, const int* __restrict__ flags,
                      void* __restrict__ dout, float* __restrict__ gsum) {
  __shared__ float part[10][200];
  int g = blockIdx.x >> 3, chunk = blockIdx.x & 7;
  int r0 = starts[g], r1 = starts[g + 1], cnt = r1 - r0;
  int ra = r0 + (cnt * chunk) / 8;
  int rb = r0 + (cnt * (chunk + 1)) / 8;
  int tid = threadIdx.x;
  int rg = tid / 25, sub = tid - rg * 25;
  int f32o = flags[0];
  if (rg < 10) {
    float acc[8];
#pragma unroll
    for (int j = 0; j < 8; ++j) acc[j] = 0.f;
    for (int r = ra + rg; r < rb; r += 10) {
      float sf = scoref[r];
      uint4 xv = *(const uint4*)(out + (size_t)r * CC + sub * 8);
      unsigned int w[4] = {xv.x, xv.y, xv.z, xv.w};
      float v[8];
#pragma unroll
      for (int j = 0; j < 4; ++j) {
        v[2*j]   = bfraw(w[j] & 0xffffu) * sf;
        v[2*j+1] = bfraw(w[j] >> 16) * sf;
        acc[2*j] += v[2*j]; acc[2*j+1] += v[2*j+1];
      }
      if (f32o) {
        float* dp = (float*)dout + (size_t)r * CC + sub * 8;
        *(float4*)dp       = make_float4(v[0], v[1], v[2], v[3]);
        *(float4*)(dp + 4) = make_float4(v[4], v[5], v[6], v[7]);
      } else {
        unsigned int o[4];
#pragma unroll
        for (int j = 0; j < 4; ++j)
          o[j] = (unsigned int)f2bfraw(v[2*j]) | ((unsigned int)f2bfraw(v[2*j+1]) << 16);
        *(uint4*)((unsigned short*)dout + (size_t)r * CC + sub * 8) = make_uint4(o[0], o[1], o[2], o[3]);
      }
    }
#pragma unroll
    for (int j = 0; j < 8; ++j) part[rg][sub * 8 + j] = acc[j];
  }
  __syncthreads();
  if (tid < 200) {
    float s = 0.f;
#pragma unroll
    for (int k = 0; k < 10; ++k) s += part[k][tid];
    atomicAdd(&gsum[g * 200 + tid], s);
  }
}

__global__ void k_gfin(const float* __restrict__ gsum, const int* __restrict__ flags,
                       void* __restrict__ dout) {
  int i = blockIdx.x * 256 + threadIdx.x;
  if (i >= GG * 200) return;
  float s = gsum[i];
  size_t o = (size_t)NN * CC + i;
  if (flags[0]) ((float*)dout)[o] = s;
  else ((unsigned short*)dout)[o] = f2bfraw(s);
}

// ---------- workspace layout (bytes; 16B-aligned) ----------
constexpr size_t O_FLAGS  = 0;
constexpr size_t O_STARTS = 16;
constexpr size_t O_MEAN   = 2080;
constexpr size_t O_RSTD   = 4128;
constexpr size_t O_SMAX   = 6176;
constexpr size_t O_SSUM   = 8224;
constexpr size_t O_SUMS   = 10272;
constexpr size_t O_PAR    = 10784;      // 41401*2, pad -> 93600
constexpr size_t O_WPACK  = 93600;      // 93184
constexpr size_t O_BATCH  = 186784;     // 400000
constexpr size_t O_EI32   = 586784;     // 3200000
constexpr size_t O_DEG    = 3786784;    // 400000
constexpr size_t O_FILL   = 4186784;    // 400000 (contiguous w/ DEG for one memset)
constexpr size_t O_ROWPTR = 4586784;    // 400128
constexpr size_t O_CSRC   = 4986912;    // 1600000
constexpr size_t O_ASRC   = 6586912;    // 1600000
constexpr size_t O_ADST   = 8186912;    // 1600000
constexpr size_t O_SREL   = 9786912;    // 400000
constexpr size_t O_SROOT  = 10186912;   // 400000
constexpr size_t O_SCORE  = 10586912;   // 400000
constexpr size_t O_SCOREF = 10986912;   // 400000
constexpr size_t O_Z      = 11386912;   // 1600000
constexpr size_t O_ESELF  = 12986912;   // 1600000
constexpr size_t O_ATT    = 14586912;   // 6400000; head reused: gacc (4KB, pre-attn) + gsum (post-k_out)
constexpr size_t O_XH     = 20986912;   // 40000000
constexpr size_t O_OUT    = 60986912;   // 40000000

extern "C" void kernel_launch(void* const* d_in, const int* in_sizes, int n_in,
                              void* d_out, int out_size, void* d_ws, size_t ws_size,
                              hipStream_t stream) {
  const void* x     = d_in[0];
  const int*  ei    = (const int*)d_in[1];
  const int*  batchr= (const int*)d_in[2];
  const void* lnw_r = d_in[3];
  const void* lnb_r = d_in[4];
  const void* Wg_r  = d_in[5];
  const void* attS_r= d_in[6];
  const void* attD_r= d_in[7];
  const void* bias_r= d_in[8];
  const void* wrel_r= d_in[9];
  const void* brel_r= d_in[10];
  const void* wroot_r=d_in[11];

  char* ws = (char*)d_ws;
  int*   flags  = (int*)(ws + O_FLAGS);
  int*   starts = (int*)(ws + O_STARTS);
  float* mean   = (float*)(ws + O_MEAN);
  float* rstd   = (float*)(ws + O_RSTD);
  float* smax   = (float*)(ws + O_SMAX);
  float* ssum   = (float*)(ws + O_SSUM);
  int*   sums   = (int*)(ws + O_SUMS);
  unsigned short* par = (unsigned short*)(ws + O_PAR);
  unsigned short* wpack = (unsigned short*)(ws + O_WPACK);
  int*   batch  = (int*)(ws + O_BATCH);
  int*   ei32   = (int*)(ws + O_EI32);
  int*   deg    = (int*)(ws + O_DEG);
  int*   fill   = (int*)(ws + O_FILL);
  int*   rowptr = (int*)(ws + O_ROWPTR);
  int*   csrc   = (int*)(ws + O_CSRC);
  float* asrc   = (float*)(ws + O_ASRC);
  float* adst   = (float*)(ws + O_ADST);
  float* srel   = (float*)(ws + O_SREL);
  float* sroot  = (float*)(ws + O_SROOT);
  float* score  = (float*)(ws + O_SCORE);
  float* scoref = (float*)(ws + O_SCOREF);
  float* z      = (float*)(ws + O_Z);
  float* eself  = (float*)(ws + O_ESELF);
  float* att    = (float*)(ws + O_ATT);
  float* gacc   = (float*)(ws + O_ATT);                 // 4KB, dead before k_attn_z
  float* gsum   = (float*)(ws + O_ATT + 4096);          // 409600B, alive only after k_out
  unsigned short* xh    = (unsigned short*)(ws + O_XH);
  unsigned short* outws = (unsigned short*)(ws + O_OUT);

  unsigned short* lnw  = par;
  unsigned short* lnb  = par + 200;
  unsigned short* Wc   = par + 400;
  unsigned short* attS = par + 40400;
  unsigned short* attD = par + 40600;
  unsigned short* bias = par + 40800;
  unsigned short* wrel = par + 41000;
  unsigned short* wroot= par + 41200;
  unsigned short* brel = par + 41400;

  hipMemsetAsync(deg, 0, 800000, stream);        // deg + fill
  hipMemsetAsync(gacc, 0, 4096, stream);         // ln stats accumulators

  k_detect    <<<1, 64, 0, stream>>>((const unsigned int*)lnw_r, (const unsigned int*)ei, flags);
  k_cvt_params<<<162, 256, 0, stream>>>(lnw_r, lnb_r, Wg_r, attS_r, attD_r, bias_r,
                                        wrel_r, brel_r, wroot_r, flags, par);
  k_cvt_edges <<<(2 * EE + 255) / 256, 256, 0, stream>>>(ei, flags, ei32, deg);
  k_cvt_idx   <<<(NN + 255) / 256, 256, 0, stream>>>(batchr, flags, batch, NN);
  k_starts    <<<(NN + 255) / 256, 256, 0, stream>>>(batch, starts);
  k_ln_stats  <<<GG * 8, 256, 0, stream>>>(x, starts, flags, gacc);
  k_ln_fin    <<<8, 64, 0, stream>>>(gacc, starts, mean, rstd);
  k_wpack     <<<(13 * 7 * 64 * 8 + 255) / 256, 256, 0, stream>>>(Wc, wpack);
  k_ngemm     <<<1563, 256, 0, stream>>>(x, batch, mean, rstd, lnw, lnb, wpack, flags, xh);
  k_attdots   <<<(NN * 4 + 255) / 256, 256, 0, stream>>>(xh, attS, attD, asrc, adst);
  k_scan1     <<<98, 256, 0, stream>>>(deg, rowptr, sums);
  k_scan2     <<<1, 128, 0, stream>>>(sums, 98);
  k_scan3     <<<98, 256, 0, stream>>>(rowptr, sums);
  k_scatter   <<<(EE + 255) / 256, 256, 0, stream>>>(ei32, rowptr, fill, csrc);
  k_attn_z    <<<(NN + 255) / 256, 256, 0, stream>>>(asrc, adst, rowptr, csrc, att, z, eself);
  k_out       <<<10000, 256, 0, stream>>>(xh, att, z, eself, rowptr, csrc, bias, wrel, wroot,
                                          outws, srel, sroot);
  hipMemsetAsync(gsum, 0, 409600, stream);       // after k_out: att region dead
  k_score     <<<(NN + 255) / 256, 256, 0, stream>>>(srel, sroot, brel, rowptr, csrc, score);
  k_gsoftmax  <<<GG, 256, 0, stream>>>(score, starts, smax, ssum);
  k_scoref    <<<(NN + 255) / 256, 256, 0, stream>>>(score, batch, smax, ssum, scoref);
  k_xpg       <<<GG * 8, 256, 0, stream>>>(outws, scoref, starts, flags, d_out, gsum);
  k_gfin      <<<(GG * 200 + 255) / 256, 256, 0, stream>>>(gsum, flags, d_out);
}

// Round 5
// 354.297 us; speedup vs baseline: 1.6322x; 1.0498x over previous
//
#include <hip/hip_runtime.h>
#include <hip/hip_bf16.h>

// Problem constants (match reference)
#define NN 100000
#define CC 200
#define EE 400000
#define GG 512
// H=4 heads, D=50

typedef __bf16 bf16x8 __attribute__((ext_vector_type(8)));
typedef float f32x4 __attribute__((ext_vector_type(4)));

__device__ __forceinline__ float bfraw(unsigned int u) { return __uint_as_float(u << 16); }
__device__ __forceinline__ unsigned short f2bfraw(float f) {
  __hip_bfloat16 b = __float2bfloat16(f);
  union { __hip_bfloat16 b; unsigned short u; } cv; cv.b = b; return cv.u;
}
__device__ __forceinline__ float hsel(float4 v, int h) {
  return h == 0 ? v.x : h == 1 ? v.y : h == 2 ? v.z : v.w;
}

// ---------- runtime dtype detection ----------
__global__ void k_detect(const unsigned int* __restrict__ lnw_raw,
                         const unsigned int* __restrict__ ei_raw, int* __restrict__ flags) {
  if (threadIdx.x == 0 && blockIdx.x == 0) {
    flags[0] = (lnw_raw[0] == 0x3F800000u) ? 1 : 0;
    flags[1] = (ei_raw[1] == 0u && ei_raw[3] == 0u && ei_raw[5] == 0u && ei_raw[7] == 0u) ? 1 : 0;
  }
}

// edges convert + fused degree histogram (dst half)
__global__ void k_cvt_edges(const int* __restrict__ raw, const int* __restrict__ flags,
                            int* __restrict__ out, int* __restrict__ deg) {
  int i = blockIdx.x * 256 + threadIdx.x;
  if (i >= 2 * EE) return;
  int v = flags[1] ? raw[2 * i] : raw[i];
  out[i] = v;
  if (i >= EE) atomicAdd(&deg[v], 1);
}

// canonical bf16 param block:
// [0:200) lnw | [200:400) lnb | [400:40400) W | [40400:40600) attS | [40600:40800) attD
// [40800:41000) bias | [41000:41200) wrel | [41200:41400) wroot | [41400] brel
__global__ void k_cvt_params(const void* lnw, const void* lnb, const void* W,
                             const void* attS, const void* attD, const void* bias,
                             const void* wrel, const void* brel, const void* wroot,
                             const int* __restrict__ flags, unsigned short* __restrict__ out) {
  int i = blockIdx.x * 256 + threadIdx.x;
  if (i > 41400) return;
  const void* p; int off;
  if (i < 200)        { p = lnw;  off = i; }
  else if (i < 400)   { p = lnb;  off = i - 200; }
  else if (i < 40400) { p = W;    off = i - 400; }
  else if (i < 40600) { p = attS; off = i - 40400; }
  else if (i < 40800) { p = attD; off = i - 40600; }
  else if (i < 41000) { p = bias; off = i - 40800; }
  else if (i < 41200) { p = wrel; off = i - 41000; }
  else if (i < 41400) { p = wroot; off = i - 41200; }
  else                { p = brel; off = 0; }
  out[i] = flags[0] ? f2bfraw(((const float*)p)[off]) : ((const unsigned short*)p)[off];
}

// ---------- batch convert + graph segment starts (batch is sorted) ----------
__global__ void k_batch(const int* __restrict__ raw, const int* __restrict__ flags,
                        int* __restrict__ batch, int* __restrict__ starts) {
  int i = blockIdx.x * 256 + threadIdx.x;
  if (i >= NN) return;
  int f = flags[1];
  int b = f ? raw[2 * i] : raw[i];
  batch[i] = b;
  int pb = (i == 0) ? -1 : (f ? raw[2 * i - 2] : raw[i - 1]);
  for (int g = pb + 1; g <= b; ++g) starts[g] = i;
  if (i == NN - 1) {
    for (int g = b + 1; g <= GG; ++g) starts[g] = NN;
  }
}

// ---------- per-graph LayerNorm stats: 8 chunks/graph, fp32 atomic partials ----------
__global__ void k_ln_stats(const void* __restrict__ x, const int* __restrict__ starts,
                           const int* __restrict__ flags, float* __restrict__ gacc) {
  __shared__ float sh1[4], sh2[4];
  int g = blockIdx.x >> 3, chunk = blockIdx.x & 7;
  int r0 = starts[g], r1 = starts[g + 1], cnt = r1 - r0;
  int ra = r0 + (cnt * chunk) / 8;
  int rb = r0 + (cnt * (chunk + 1)) / 8;
  float s1 = 0.f, s2 = 0.f;
  if (flags[0]) {
    const float4* xv = (const float4*)x;
    for (int i = ra * 50 + (int)threadIdx.x; i < rb * 50; i += 256) {
      float4 r = xv[i];
      s1 += r.x + r.y + r.z + r.w;
      s2 += r.x * r.x + r.y * r.y + r.z * r.z + r.w * r.w;
    }
  } else {
    const uint4* xv = (const uint4*)x;
    for (int i = ra * 25 + (int)threadIdx.x; i < rb * 25; i += 256) {
      uint4 r = xv[i];
      unsigned int w[4] = {r.x, r.y, r.z, r.w};
#pragma unroll
      for (int j = 0; j < 4; ++j) {
        float a = bfraw(w[j] & 0xffffu);
        float b = bfraw(w[j] >> 16);
        s1 += a + b; s2 += a * a + b * b;
      }
    }
  }
#pragma unroll
  for (int o = 32; o > 0; o >>= 1) { s1 += __shfl_down(s1, o, 64); s2 += __shfl_down(s2, o, 64); }
  if ((threadIdx.x & 63) == 0) { sh1[threadIdx.x >> 6] = s1; sh2[threadIdx.x >> 6] = s2; }
  __syncthreads();
  if (threadIdx.x == 0) {
    atomicAdd(&gacc[g * 2],     sh1[0] + sh1[1] + sh1[2] + sh1[3]);
    atomicAdd(&gacc[g * 2 + 1], sh2[0] + sh2[1] + sh2[2] + sh2[3]);
  }
}

__global__ void k_ln_fin(const float* __restrict__ gacc, const int* __restrict__ starts,
                         float* __restrict__ mean, float* __restrict__ rstd) {
  int g = blockIdx.x * 64 + threadIdx.x;
  if (g >= GG) return;
  int cnt = starts[g + 1] - starts[g];
  if (cnt > 0) {
    float denom = (float)cnt * (float)CC;
    float m = gacc[g * 2] / denom;
    float var = gacc[g * 2 + 1] / denom - m * m;
    mean[g] = m;
    rstd[g] = rsqrtf(var + 1e-5f);
  } else { mean[g] = 0.f; rstd[g] = 0.f; }
}

// ---------- pack W into MFMA B-fragment order ----------
__global__ void k_wpack(const unsigned short* __restrict__ W, unsigned short* __restrict__ wp) {
  int idx = blockIdx.x * 256 + threadIdx.x;
  if (idx >= 13 * 7 * 64 * 8) return;
  int j = idx & 7;
  int rest = idx >> 3;
  int l = rest & 63;
  int ts = rest >> 6;
  int s = ts % 7, t = ts / 7;
  int k = s * 32 + (l >> 4) * 8 + j;
  int n = t * 16 + (l & 15);
  wp[idx] = (k < CC && n < CC) ? W[k * CC + n] : (unsigned short)0;
}

// ---------- fused LN-normalize + ELU + GEMM + attention dots ----------
// xh = elu(norm(x)) @ W computed in-register from x; a_src/a_dst from the
// MFMA accumulators via predicated per-head FMAs + 16-lane shuffle reduce.
__global__ void k_ngemm(const void* __restrict__ x, const int* __restrict__ batch,
                        const float* __restrict__ mean, const float* __restrict__ rstd,
                        const unsigned short* __restrict__ lnw, const unsigned short* __restrict__ lnb,
                        const unsigned short* __restrict__ attS, const unsigned short* __restrict__ attD,
                        const unsigned short* __restrict__ wp, const int* __restrict__ flags,
                        unsigned short* __restrict__ xh,
                        float* __restrict__ asrc, float* __restrict__ adst) {
  int gw = (blockIdx.x * 256 + threadIdx.x) >> 6;
  int lane = threadIdx.x & 63;
  int mbase = gw * 16;
  if (mbase >= NN) return;
  int quad = lane >> 4, l15 = lane & 15;
  int row = mbase + l15;
  int b = batch[row];
  float m = mean[b], rs = rstd[b];
  bool f32in = flags[0] != 0;
  f32x4 acc[13];
#pragma unroll
  for (int t = 0; t < 13; ++t) { f32x4 zz = {0.f, 0.f, 0.f, 0.f}; acc[t] = zz; }
  const bf16x8* wv = (const bf16x8*)wp;
#pragma unroll
  for (int s = 0; s < 7; ++s) {
    int kb = s * 32 + quad * 8;
    union { bf16x8 v; unsigned short u[8]; unsigned int w[4]; } af;
    if (kb < CC) {   // only s==6 && quad>=1 exceed; those MFMA against zero B-frags
      float v[8];
      if (f32in) {
        const float* xp = (const float*)x + (size_t)row * CC + kb;
        float4 a = *(const float4*)xp, c = *(const float4*)(xp + 4);
        v[0]=a.x; v[1]=a.y; v[2]=a.z; v[3]=a.w; v[4]=c.x; v[5]=c.y; v[6]=c.z; v[7]=c.w;
      } else {
        uint4 r = *(const uint4*)((const unsigned short*)x + (size_t)row * CC + kb);
        unsigned int w[4] = {r.x, r.y, r.z, r.w};
#pragma unroll
        for (int j = 0; j < 4; ++j) { v[2*j] = bfraw(w[j] & 0xffffu); v[2*j+1] = bfraw(w[j] >> 16); }
      }
      uint4 wv4 = *(const uint4*)(lnw + kb);
      uint4 bv4 = *(const uint4*)(lnb + kb);
      unsigned int ww[4] = {wv4.x, wv4.y, wv4.z, wv4.w};
      unsigned int bb[4] = {bv4.x, bv4.y, bv4.z, bv4.w};
#pragma unroll
      for (int j = 0; j < 4; ++j) {
        float t0 = (v[2*j]   - m) * rs * bfraw(ww[j] & 0xffffu) + bfraw(bb[j] & 0xffffu);
        float t1 = (v[2*j+1] - m) * rs * bfraw(ww[j] >> 16)     + bfraw(bb[j] >> 16);
        t0 = t0 > 0.f ? t0 : __expf(t0) - 1.f;
        t1 = t1 > 0.f ? t1 : __expf(t1) - 1.f;
        af.u[2*j]   = f2bfraw(t0);
        af.u[2*j+1] = f2bfraw(t1);
      }
    } else {
#pragma unroll
      for (int j = 0; j < 4; ++j) af.w[j] = 0u;
    }
#pragma unroll
    for (int t = 0; t < 13; ++t) {
      bf16x8 bf = wv[(t * 7 + s) * 64 + lane];
      acc[t] = __builtin_amdgcn_mfma_f32_16x16x32_bf16(af.v, bf, acc[t], 0, 0, 0);
    }
  }
  // C/D layout: col = lane&15, row = quad*4 + reg
#pragma unroll
  for (int t = 0; t < 13; ++t) {
    int c = t * 16 + l15;
    if (c < CC) {
#pragma unroll
      for (int r = 0; r < 4; ++r) {
        int mrow = mbase + quad * 4 + r;
        xh[(size_t)mrow * CC + c] = f2bfraw(acc[t][r]);
      }
    }
  }
  // attention dots epilogue: a_src[n,h] = sum_c xh[n,c]*attS[c] (c in head h)
  float wsv[13], wdv[13]; int hv[13];
#pragma unroll
  for (int t = 0; t < 13; ++t) {
    int c = t * 16 + l15;
    bool ok = c < CC;
    hv[t]  = ok ? c / 50 : 0;
    wsv[t] = ok ? bfraw(attS[ok ? c : 0]) : 0.f;
    wdv[t] = ok ? bfraw(attD[ok ? c : 0]) : 0.f;
  }
#pragma unroll
  for (int r = 0; r < 4; ++r) {
    float ps[4] = {0.f, 0.f, 0.f, 0.f}, pd[4] = {0.f, 0.f, 0.f, 0.f};
#pragma unroll
    for (int t = 0; t < 13; ++t) {
      float v = acc[t][r];
      float fs = v * wsv[t], fd = v * wdv[t];
#pragma unroll
      for (int j = 0; j < 4; ++j) {
        ps[j] += (hv[t] == j) ? fs : 0.f;
        pd[j] += (hv[t] == j) ? fd : 0.f;
      }
    }
#pragma unroll
    for (int mm = 1; mm < 16; mm <<= 1) {
#pragma unroll
      for (int j = 0; j < 4; ++j) {
        ps[j] += __shfl_xor(ps[j], mm, 64);
        pd[j] += __shfl_xor(pd[j], mm, 64);
      }
    }
    if (l15 == 0) {
      int rw = mbase + quad * 4 + r;
      *(float4*)(asrc + (size_t)rw * 4) = make_float4(ps[0], ps[1], ps[2], ps[3]);
      *(float4*)(adst + (size_t)rw * 4) = make_float4(pd[0], pd[1], pd[2], pd[3]);
    }
  }
}

// ---------- CSR build ----------
__global__ void k_scan1(const int* __restrict__ deg, int* __restrict__ rowptr, int* __restrict__ sums) {
  __shared__ int sh[256];
  int tid = threadIdx.x;
  int base = blockIdx.x * 1024 + tid * 4;
  int v[4]; int s = 0;
#pragma unroll
  for (int j = 0; j < 4; ++j) { int i = base + j; v[j] = (i < NN) ? deg[i] : 0; s += v[j]; }
  sh[tid] = s;
  __syncthreads();
  for (int o = 1; o < 256; o <<= 1) {
    int t = (tid >= o) ? sh[tid - o] : 0;
    __syncthreads();
    sh[tid] += t;
    __syncthreads();
  }
  int run = sh[tid] - s;
#pragma unroll
  for (int j = 0; j < 4; ++j) { int i = base + j; if (i < NN) rowptr[i] = run; run += v[j]; }
  if (tid == 255) sums[blockIdx.x] = sh[255];
}

__global__ void k_scan2(int* __restrict__ sums, int nb) {
  __shared__ int sh[128];
  int tid = threadIdx.x;
  int v = (tid < nb) ? sums[tid] : 0;
  sh[tid] = v;
  __syncthreads();
  for (int o = 1; o < 128; o <<= 1) {
    int t = (tid >= o) ? sh[tid - o] : 0;
    __syncthreads();
    sh[tid] += t;
    __syncthreads();
  }
  if (tid < nb) sums[tid] = sh[tid] - v;   // exclusive
}

__global__ void k_scan3(int* __restrict__ rowptr, const int* __restrict__ sums) {
  int tid = threadIdx.x;
  int add = sums[blockIdx.x];
  int base = blockIdx.x * 1024 + tid * 4;
#pragma unroll
  for (int j = 0; j < 4; ++j) { int i = base + j; if (i < NN) rowptr[i] += add; }
  if (blockIdx.x == 0 && tid == 0) rowptr[NN] = EE;
}

__global__ void k_scatter(const int* __restrict__ ei32, const int* __restrict__ rowptr,
                          int* __restrict__ fill, int* __restrict__ csrc) {
  int e = blockIdx.x * 256 + threadIdx.x;
  if (e >= EE) return;
  int s = ei32[e], d = ei32[EE + e];
  int pos = rowptr[d] + atomicAdd(&fill[d], 1);
  csrc[pos] = s;
}

// ---------- out = attention aggregation + bias; inline softmax; fused score dots ----------
// 25 lanes/node x uint4 (8 ch); 10 nodes per 256-thread block; edge loop unrolled x2.
// e-weights recomputed inline from asrc/adst; z accumulated in-register.
__global__ void k_out(const unsigned short* __restrict__ xh, const float* __restrict__ asrc,
                      const float* __restrict__ adst,
                      const int* __restrict__ rowptr, const int* __restrict__ csrc,
                      const unsigned short* __restrict__ bias, const unsigned short* __restrict__ wrel,
                      const unsigned short* __restrict__ wroot,
                      unsigned short* __restrict__ out,
                      float* __restrict__ srel, float* __restrict__ sroot) {
  __shared__ float sA[256], sB[256];
  int tid = threadIdx.x;
  int local = tid / 25;
  int sub = tid - local * 25;
  int n = blockIdx.x * 10 + local;
  bool active = (local < 10) && (n < NN);
  float pr = 0.f, pq = 0.f;
  if (active) {
    int c0 = sub * 8;
    int hh0 = c0 / 50;
    int hh1 = hh0 < 3 ? hh0 + 1 : hh0;
    int bnd = (hh0 + 1) * 50;
    bool cr[8];
#pragma unroll
    for (int j = 0; j < 8; ++j) cr[j] = (c0 + j) >= bnd;
    float4 adn = *(const float4*)(adst + (size_t)n * 4);
    float4 asn = *(const float4*)(asrc + (size_t)n * 4);
    float ad_lo = hsel(adn, hh0), ad_hi = hsel(adn, hh1);
    float al_lo = hsel(asn, hh0) + ad_lo;
    float al_hi = hsel(asn, hh1) + ad_hi;
    al_lo = al_lo > 0.f ? al_lo : 0.2f * al_lo;
    al_hi = al_hi > 0.f ? al_hi : 0.2f * al_hi;
    float e_lo = __expf(al_lo), e_hi = __expf(al_hi);
    float z_lo = e_lo, z_hi = e_hi;
    float acc[8];
    {
      uint4 xv = *(const uint4*)(xh + (size_t)n * CC + c0);
      unsigned int w[4] = {xv.x, xv.y, xv.z, xv.w};
#pragma unroll
      for (int j = 0; j < 4; ++j) {
        float lo = bfraw(w[j] & 0xffffu), hi = bfraw(w[j] >> 16);
        acc[2*j]   = (cr[2*j]   ? e_hi : e_lo) * lo;
        acc[2*j+1] = (cr[2*j+1] ? e_hi : e_lo) * hi;
      }
    }
    int p0 = rowptr[n], p1 = rowptr[n + 1];
    int p = p0;
    for (; p + 2 <= p1; p += 2) {
      int s0 = csrc[p], s1 = csrc[p + 1];
      uint4 g0 = *(const uint4*)(xh + (size_t)s0 * CC + c0);
      uint4 g1 = *(const uint4*)(xh + (size_t)s1 * CC + c0);
      float4 av0 = *(const float4*)(asrc + (size_t)s0 * 4);
      float4 av1 = *(const float4*)(asrc + (size_t)s1 * 4);
      float b0lo = hsel(av0, hh0) + ad_lo, b0hi = hsel(av0, hh1) + ad_hi;
      float b1lo = hsel(av1, hh0) + ad_lo, b1hi = hsel(av1, hh1) + ad_hi;
      b0lo = b0lo > 0.f ? b0lo : 0.2f * b0lo;
      b0hi = b0hi > 0.f ? b0hi : 0.2f * b0hi;
      b1lo = b1lo > 0.f ? b1lo : 0.2f * b1lo;
      b1hi = b1hi > 0.f ? b1hi : 0.2f * b1hi;
      float a0lo = __expf(b0lo), a0hi = __expf(b0hi);
      float a1lo = __expf(b1lo), a1hi = __expf(b1hi);
      z_lo += a0lo + a1lo; z_hi += a0hi + a1hi;
      unsigned int w0[4] = {g0.x, g0.y, g0.z, g0.w};
      unsigned int w1[4] = {g1.x, g1.y, g1.z, g1.w};
#pragma unroll
      for (int j = 0; j < 4; ++j) {
        acc[2*j]   += (cr[2*j]   ? a0hi : a0lo) * bfraw(w0[j] & 0xffffu);
        acc[2*j+1] += (cr[2*j+1] ? a0hi : a0lo) * bfraw(w0[j] >> 16);
      }
#pragma unroll
      for (int j = 0; j < 4; ++j) {
        acc[2*j]   += (cr[2*j]   ? a1hi : a1lo) * bfraw(w1[j] & 0xffffu);
        acc[2*j+1] += (cr[2*j+1] ? a1hi : a1lo) * bfraw(w1[j] >> 16);
      }
    }
    if (p < p1) {
      int s0 = csrc[p];
      uint4 g0 = *(const uint4*)(xh + (size_t)s0 * CC + c0);
      float4 av0 = *(const float4*)(asrc + (size_t)s0 * 4);
      float b0lo = hsel(av0, hh0) + ad_lo, b0hi = hsel(av0, hh1) + ad_hi;
      b0lo = b0lo > 0.f ? b0lo : 0.2f * b0lo;
      b0hi = b0hi > 0.f ? b0hi : 0.2f * b0hi;
      float a0lo = __expf(b0lo), a0hi = __expf(b0hi);
      z_lo += a0lo; z_hi += a0hi;
      unsigned int w0[4] = {g0.x, g0.y, g0.z, g0.w};
#pragma unroll
      for (int j = 0; j < 4; ++j) {
        acc[2*j]   += (cr[2*j]   ? a0hi : a0lo) * bfraw(w0[j] & 0xffffu);
        acc[2*j+1] += (cr[2*j+1] ? a0hi : a0lo) * bfraw(w0[j] >> 16);
      }
    }
    float rz_lo = 1.f / (z_lo + 1e-16f);
    float rz_hi = 1.f / (z_hi + 1e-16f);
    uint4 bv = *(const uint4*)(bias + c0);
    uint4 rv = *(const uint4*)(wrel + c0);
    uint4 qv = *(const uint4*)(wroot + c0);
    unsigned int bw[4] = {bv.x, bv.y, bv.z, bv.w};
    unsigned int rw[4] = {rv.x, rv.y, rv.z, rv.w};
    unsigned int qw[4] = {qv.x, qv.y, qv.z, qv.w};
    unsigned int ow[4];
#pragma unroll
    for (int j = 0; j < 4; ++j) {
      float v0 = acc[2*j]   * (cr[2*j]   ? rz_hi : rz_lo) + bfraw(bw[j] & 0xffffu);
      float v1 = acc[2*j+1] * (cr[2*j+1] ? rz_hi : rz_lo) + bfraw(bw[j] >> 16);
      ow[j] = (unsigned int)f2bfraw(v0) | ((unsigned int)f2bfraw(v1) << 16);
      pr += v0 * bfraw(rw[j] & 0xffffu) + v1 * bfraw(rw[j] >> 16);
      pq += v0 * bfraw(qw[j] & 0xffffu) + v1 * bfraw(qw[j] >> 16);
    }
    *(uint4*)(out + (size_t)n * CC + c0) = make_uint4(ow[0], ow[1], ow[2], ow[3]);
  }
  sA[tid] = pr; sB[tid] = pq;
  __syncthreads();
  if (active && sub == 0) {
    float a = 0.f, b = 0.f;
#pragma unroll
    for (int k = 0; k < 25; ++k) { a += sA[tid + k]; b += sB[tid + k]; }
    srel[n] = a; sroot[n] = b;
  }
}

// ---------- SAGPool score (gather unrolled x2) ----------
__global__ void k_score(const float* __restrict__ srel, const float* __restrict__ sroot,
                        const unsigned short* __restrict__ brel, const int* __restrict__ rowptr,
                        const int* __restrict__ csrc, float* __restrict__ score) {
  int n = blockIdx.x * 256 + threadIdx.x;
  if (n >= NN) return;
  float sc = bfraw(brel[0]) + sroot[n];
  int p0 = rowptr[n], p1 = rowptr[n + 1];
  int p = p0;
  float s0 = 0.f, s1 = 0.f;
  for (; p + 2 <= p1; p += 2) { s0 += srel[csrc[p]]; s1 += srel[csrc[p + 1]]; }
  if (p < p1) s0 += srel[csrc[p]];
  score[n] = sc + s0 + s1;
}

// ---------- per-graph softmax stats ----------
__global__ void k_gsoftmax(const float* __restrict__ score, const int* __restrict__ starts,
                           float* __restrict__ smax, float* __restrict__ ssum) {
  __shared__ float sh[4];
  __shared__ float bc;
  int g = blockIdx.x;
  int r0 = starts[g], r1 = starts[g + 1];
  float m = -3.0e38f;
  for (int i = r0 + (int)threadIdx.x; i < r1; i += 256) m = fmaxf(m, score[i]);
#pragma unroll
  for (int o = 32; o > 0; o >>= 1) m = fmaxf(m, __shfl_down(m, o, 64));
  if ((threadIdx.x & 63) == 0) sh[threadIdx.x >> 6] = m;
  __syncthreads();
  if (threadIdx.x == 0) bc = fmaxf(fmaxf(sh[0], sh[1]), fmaxf(sh[2], sh[3]));
  __syncthreads();
  float mm = bc;
  float s = 0.f;
  for (int i = r0 + (int)threadIdx.x; i < r1; i += 256) s += expf(score[i] - mm);
#pragma unroll
  for (int o = 32; o > 0; o >>= 1) s += __shfl_down(s, o, 64);
  if ((threadIdx.x & 63) == 0) sh[threadIdx.x >> 6] = s;
  __syncthreads();
  if (threadIdx.x == 0) { smax[g] = mm; ssum[g] = sh[0] + sh[1] + sh[2] + sh[3]; }
}

// ---------- xp = out*softmax(score) -> d_out, + per-graph fp32 partial sums ----------
__global__ void k_xpg(const unsigned short* __restrict__ out, const float* __restrict__ score,
                      const float* __restrict__ smax, const float* __restrict__ ssum,
                      const int* __restrict__ starts, const int* __restrict__ flags,
                      void* __restrict__ dout, float* __restrict__ gsum) {
  __shared__ float part[10][200];
  int g = blockIdx.x >> 3, chunk = blockIdx.x & 7;
  int r0 = starts[g], r1 = starts[g + 1], cnt = r1 - r0;
  int ra = r0 + (cnt * chunk) / 8;
  int rb = r0 + (cnt * (chunk + 1)) / 8;
  int tid = threadIdx.x;
  int rg = tid / 25, sub = tid - rg * 25;
  int f32o = flags[0];
  float sm = smax[g], si = ssum[g];
  float rsi = (si > 0.f) ? 1.f / si : 0.f;
  if (rg < 10) {
    float acc[8];
#pragma unroll
    for (int j = 0; j < 8; ++j) acc[j] = 0.f;
    for (int r = ra + rg; r < rb; r += 10) {
      float sf = __expf(score[r] - sm) * rsi;
      uint4 xv = *(const uint4*)(out + (size_t)r * CC + sub * 8);
      unsigned int w[4] = {xv.x, xv.y, xv.z, xv.w};
      float v[8];
#pragma unroll
      for (int j = 0; j < 4; ++j) {
        v[2*j]   = bfraw(w[j] & 0xffffu) * sf;
        v[2*j+1] = bfraw(w[j] >> 16) * sf;
        acc[2*j] += v[2*j]; acc[2*j+1] += v[2*j+1];
      }
      if (f32o) {
        float* dp = (float*)dout + (size_t)r * CC + sub * 8;
        *(float4*)dp       = make_float4(v[0], v[1], v[2], v[3]);
        *(float4*)(dp + 4) = make_float4(v[4], v[5], v[6], v[7]);
      } else {
        unsigned int o[4];
#pragma unroll
        for (int j = 0; j < 4; ++j)
          o[j] = (unsigned int)f2bfraw(v[2*j]) | ((unsigned int)f2bfraw(v[2*j+1]) << 16);
        *(uint4*)((unsigned short*)dout + (size_t)r * CC + sub * 8) = make_uint4(o[0], o[1], o[2], o[3]);
      }
    }
#pragma unroll
    for (int j = 0; j < 8; ++j) part[rg][sub * 8 + j] = acc[j];
  }
  __syncthreads();
  if (tid < 200) {
    float s = 0.f;
#pragma unroll
    for (int k = 0; k < 10; ++k) s += part[k][tid];
    atomicAdd(&gsum[g * 200 + tid], s);
  }
}

__global__ void k_gfin(const float* __restrict__ gsum, const int* __restrict__ flags,
                       void* __restrict__ dout) {
  int i = blockIdx.x * 256 + threadIdx.x;
  if (i >= GG * 200) return;
  float s = gsum[i];
  size_t o = (size_t)NN * CC + i;
  if (flags[0]) ((float*)dout)[o] = s;
  else ((unsigned short*)dout)[o] = f2bfraw(s);
}

// ---------- workspace layout (bytes; 16B-aligned) ----------
constexpr size_t O_FLAGS  = 0;
constexpr size_t O_STARTS = 16;
constexpr size_t O_MEAN   = 2080;
constexpr size_t O_RSTD   = 4128;
constexpr size_t O_SMAX   = 6176;
constexpr size_t O_SSUM   = 8224;
constexpr size_t O_SUMS   = 10272;
constexpr size_t O_PAR    = 10784;      // 41401*2, pad -> 93600
constexpr size_t O_WPACK  = 93600;      // 93184
constexpr size_t O_BATCH  = 186784;     // 400000
constexpr size_t O_EI32   = 586784;     // 3200000
constexpr size_t O_DEG    = 3786784;    // 400000
constexpr size_t O_FILL   = 4186784;    // 400000 (contiguous w/ DEG for one memset)
constexpr size_t O_ROWPTR = 4586784;    // 400128
constexpr size_t O_CSRC   = 4986912;    // 1600000
constexpr size_t O_ASRC   = 6586912;    // 1600000
constexpr size_t O_ADST   = 8186912;    // 1600000
constexpr size_t O_SREL   = 9786912;    // 400000
constexpr size_t O_SROOT  = 10186912;   // 400000
constexpr size_t O_SCORE  = 10586912;   // 400000
constexpr size_t O_GACC   = 10986912;   // 4096 (dead after k_ln_fin)
constexpr size_t O_GSUM   = 10991008;   // 409600
constexpr size_t O_XH     = 11400608;   // 40000000
constexpr size_t O_OUT    = 51400608;   // 40000000

extern "C" void kernel_launch(void* const* d_in, const int* in_sizes, int n_in,
                              void* d_out, int out_size, void* d_ws, size_t ws_size,
                              hipStream_t stream) {
  const void* x     = d_in[0];
  const int*  ei    = (const int*)d_in[1];
  const int*  batchr= (const int*)d_in[2];
  const void* lnw_r = d_in[3];
  const void* lnb_r = d_in[4];
  const void* Wg_r  = d_in[5];
  const void* attS_r= d_in[6];
  const void* attD_r= d_in[7];
  const void* bias_r= d_in[8];
  const void* wrel_r= d_in[9];
  const void* brel_r= d_in[10];
  const void* wroot_r=d_in[11];

  char* ws = (char*)d_ws;
  int*   flags  = (int*)(ws + O_FLAGS);
  int*   starts = (int*)(ws + O_STARTS);
  float* mean   = (float*)(ws + O_MEAN);
  float* rstd   = (float*)(ws + O_RSTD);
  float* smax   = (float*)(ws + O_SMAX);
  float* ssum   = (float*)(ws + O_SSUM);
  int*   sums   = (int*)(ws + O_SUMS);
  unsigned short* par = (unsigned short*)(ws + O_PAR);
  unsigned short* wpack = (unsigned short*)(ws + O_WPACK);
  int*   batch  = (int*)(ws + O_BATCH);
  int*   ei32   = (int*)(ws + O_EI32);
  int*   deg    = (int*)(ws + O_DEG);
  int*   fill   = (int*)(ws + O_FILL);
  int*   rowptr = (int*)(ws + O_ROWPTR);
  int*   csrc   = (int*)(ws + O_CSRC);
  float* asrc   = (float*)(ws + O_ASRC);
  float* adst   = (float*)(ws + O_ADST);
  float* srel   = (float*)(ws + O_SREL);
  float* sroot  = (float*)(ws + O_SROOT);
  float* score  = (float*)(ws + O_SCORE);
  float* gacc   = (float*)(ws + O_GACC);
  float* gsum   = (float*)(ws + O_GSUM);
  unsigned short* xh    = (unsigned short*)(ws + O_XH);
  unsigned short* outws = (unsigned short*)(ws + O_OUT);

  unsigned short* lnw  = par;
  unsigned short* lnb  = par + 200;
  unsigned short* Wc   = par + 400;
  unsigned short* attS = par + 40400;
  unsigned short* attD = par + 40600;
  unsigned short* bias = par + 40800;
  unsigned short* wrel = par + 41000;
  unsigned short* wroot= par + 41200;
  unsigned short* brel = par + 41400;

  hipMemsetAsync(deg, 0, 800000, stream);        // deg + fill
  hipMemsetAsync(gacc, 0, 4096 + 409600, stream);// gacc + gsum (contiguous)

  k_detect    <<<1, 64, 0, stream>>>((const unsigned int*)lnw_r, (const unsigned int*)ei, flags);
  k_cvt_params<<<162, 256, 0, stream>>>(lnw_r, lnb_r, Wg_r, attS_r, attD_r, bias_r,
                                        wrel_r, brel_r, wroot_r, flags, par);
  k_cvt_edges <<<(2 * EE + 255) / 256, 256, 0, stream>>>(ei, flags, ei32, deg);
  k_batch     <<<(NN + 255) / 256, 256, 0, stream>>>(batchr, flags, batch, starts);
  k_ln_stats  <<<GG * 8, 256, 0, stream>>>(x, starts, flags, gacc);
  k_ln_fin    <<<8, 64, 0, stream>>>(gacc, starts, mean, rstd);
  k_wpack     <<<(13 * 7 * 64 * 8 + 255) / 256, 256, 0, stream>>>(Wc, wpack);
  k_ngemm     <<<1563, 256, 0, stream>>>(x, batch, mean, rstd, lnw, lnb, attS, attD,
                                         wpack, flags, xh, asrc, adst);
  k_scan1     <<<98, 256, 0, stream>>>(deg, rowptr, sums);
  k_scan2     <<<1, 128, 0, stream>>>(sums, 98);
  k_scan3     <<<98, 256, 0, stream>>>(rowptr, sums);
  k_scatter   <<<(EE + 255) / 256, 256, 0, stream>>>(ei32, rowptr, fill, csrc);
  k_out       <<<10000, 256, 0, stream>>>(xh, asrc, adst, rowptr, csrc, bias, wrel, wroot,
                                          outws, srel, sroot);
  k_score     <<<(NN + 255) / 256, 256, 0, stream>>>(srel, sroot, brel, rowptr, csrc, score);
  k_gsoftmax  <<<GG, 256, 0, stream>>>(score, starts, smax, ssum);
  k_xpg       <<<GG * 8, 256, 0, stream>>>(outws, score, smax, ssum, starts, flags, d_out, gsum);
  k_gfin      <<<(GG * 200 + 255) / 256, 256, 0, stream>>>(gsum, flags, d_out);
}